// Round 7
// baseline (1147.982 us; speedup 1.0000x reference)
//
#include <hip/hip_runtime.h>
#include <hip/hip_bf16.h>

// DynamisCropClassifier — ROUND 13: FUSED single kernel.
//   Rationale: R6 accounting = k_scan 112 + k_attn ~90 + ~75us kernel-boundary
//   gap. Dependency is per-block only -> fuse. 1024 blocks x 256 thr x 40960B
//   LDS = EXACTLY 4 blocks/CU, all blocks resident (required: scan is 112us
//   serial per block; a second dispatch round would double it).
//   Wave (blockIdx.x&3) runs the scan (spreads across SIMDs); other 3 waves
//   pre-stage xz x-part/pads + phase-B FT tiles under the scan's shadow.
//   Attention reads innov/state from LDS (sInn7/sSt7, x7-packed, 7168B) --
//   values oclamp-identical to the old global round-trip. Scan body = R1-style
//   (116 reg, fits the 128 unified cap of launch_bounds(256,4); R6's
//   single-asm variant needs ~176 unified incl. AGPRs -> would spill).
//   All arithmetic values + orders preserved; absmax tripwire 0.0234375.
// LDS map (bytes):
//   [0,18432)     sAin/ctxb (phase C onward); row pads: r0=zslot, r1-16=pooled,
//                 r17=gates, r18=energy (all < byte 2752)
//   [2752,16368)  SCAN: sX 2752..12992, sKt ..15488, sH ..15744, sM ..15952,
//                 sS ..16160, sU ..16368 (dead before sAin written)
//   [18432,28672) xz (A-C) | heads: sVT ..22784 + sP(w)=22784+w*4352
//                 | post-heads: sOut [18432,36864)
//   [28672,33792) FT (B-C) | heads: sQ pitch24 [28672,34816)
//   [34816,40960) sK pitch24 (heads)
//   [33792,37376) sInn7 / [37376,40960) sSt7: written by scan, consumed
//                 before sync2; first clobber = heads sQ/sK/sP (post S4). ok.

typedef unsigned short u16;
typedef __attribute__((ext_vector_type(8))) short bfrag;   // 8 x bf16 (4 VGPR)
typedef __attribute__((ext_vector_type(4))) float ffrag;   // 4 x f32 acc

#define MFMA16(a,b,c) __builtin_amdgcn_mfma_f32_16x16x32_bf16((a),(b),(c),0,0,0)
#define WSYNC() __builtin_amdgcn_wave_barrier()

// ---- output element offsets (fp32 elements) ----
#define O_CROP  0
#define O_PHENO 3072
#define O_INNOV 920576
#define O_UNC   1838080
#define O_XFIN  1839104
#define O_STATE 1846272

static __device__ __forceinline__ float i2f(int i){union{int i;float f;}u;u.i=i;return u.f;}
static __device__ __forceinline__ int f2i(float f){union{int i;float f;}u;u.f=f;return u.i;}
#define DPPADD(v,ctrl) ((v) + i2f(__builtin_amdgcn_update_dpp(0, f2i(v), (ctrl), 0xF, 0xF, true)))
#define DPPMAX(v,ctrl) fmaxf((v), i2f(__builtin_amdgcn_update_dpp(0, f2i(v), (ctrl), 0xF, 0xF, true)))

static __device__ __forceinline__ u16 f2us(float f) {   // RNE fp32 -> bf16 bits
  union { float f; unsigned int i; } v; v.f = f;
  unsigned int r = v.i + 0x7FFFu + ((v.i >> 16) & 1u);
  return (u16)(r >> 16);
}
static __device__ __forceinline__ float oclamp(float v) {
  v = fmaxf(v, -1.0e30f); v = fminf(v, 1.0e30f); return v;
}
static __device__ __forceinline__ float rfl(float x) {
  return i2f(__builtin_amdgcn_readfirstlane(f2i(x)));
}
static __device__ __forceinline__ float rlane(float x, int l) {
  return i2f(__builtin_amdgcn_readlane(f2i(x), l));
}
static __device__ __forceinline__ void keep4(float4 v) {
  asm volatile("" :: "v"(v.x), "v"(v.y), "v"(v.z), "v"(v.w));
}

// ---- fragment helpers ----
static __device__ __forceinline__ bfrag ldfrag(const u16* t, int row0, int pitch, int koff) {
  int l = threadIdx.x & 63;
  return *(const bfrag*)(t + (row0 + (l & 15))*pitch + koff + ((l >> 4) << 3));
}
static __device__ __forceinline__ bfrag ldQK(const u16* base, const u16* zslot, int row0) {
  int l = threadIdx.x & 63;
  int g = l >> 4;
  const u16* p = (g < 2) ? (base + (row0 + (l & 15))*24 + g*8) : zslot;
  return *(const bfrag*)p;
}
static __device__ __forceinline__ void stfrag(u16* t, int row0, int col0, int pitch, ffrag d) {
  int l = threadIdx.x & 63;
  int col = col0 + (l & 15);
  int r0 = row0 + ((l >> 4) << 2);
  #pragma unroll
  for (int r = 0; r < 4; r++) t[(r0 + r)*pitch + col] = f2us(d[r]);
}
static __device__ __forceinline__ void stfragT(u16* t, int row0, int col0, int pitch, ffrag d) {
  int l = threadIdx.x & 63;
  int n = col0 + (l & 15);
  int m0 = row0 + ((l >> 4) << 2);
  ushort4 pk;
  pk.x = f2us(d[0]); pk.y = f2us(d[1]); pk.z = f2us(d[2]); pk.w = f2us(d[3]);
  *(ushort4*)(t + n*pitch + m0) = pk;
}
static __device__ __forceinline__ bfrag ldWG(const float* __restrict__ W, int n0, int koff) {
  int l = threadIdx.x & 63;
  int n = n0 + (l & 15);
  int k0 = koff + ((l >> 4) << 3);
  bfrag r;
  #pragma unroll
  for (int kk = 0; kk < 8; kk++) r[kk] = (short)f2us(W[(k0 + kk)*64 + n]);
  return r;
}
static __device__ __forceinline__ bfrag ldPnG(const float* __restrict__ Wpn, int koff) {
  int l = threadIdx.x & 63;
  int n = l & 15;
  int k0 = koff + ((l >> 4) << 3);
  bfrag r;
  #pragma unroll
  for (int kk = 0; kk < 8; kk++) {
    float v = (n < 7) ? Wpn[(k0 + kk)*7 + n] : 0.f;
    r[kk] = (short)f2us(v);
  }
  return r;
}
static __device__ __forceinline__ bfrag ldInG(const float* __restrict__ W_in,
                                              const float* __restrict__ b_in,
                                              int r0, int koff) {
  int l = threadIdx.x & 63;
  int r = r0 + (l & 15);
  int k0 = koff + ((l >> 4) << 3);
  bfrag o;
  #pragma unroll
  for (int kk = 0; kk < 8; kk++) {
    float v = 0.f;
    if (r < 17) v = W_in[r*64 + k0 + kk];
    else if (r == 17) v = b_in[k0 + kk];
    o[kk] = (short)f2us(v);
  }
  return o;
}

#define PAD_F(smem, r, j) (((float*)((smem) + (r)*144 + 128))[j])

__global__ __launch_bounds__(256, 4) void k_fused(
    const float* __restrict__ xg,
    const float* __restrict__ W_in, const float* __restrict__ b_in,
    const float* __restrict__ W_exec, const float* __restrict__ b_exec,
    const float* __restrict__ W_meas, const float* __restrict__ b_meas,
    const float* __restrict__ A,
    const float* __restrict__ Wq, const float* __restrict__ bq,
    const float* __restrict__ Wk, const float* __restrict__ bk,
    const float* __restrict__ Wv, const float* __restrict__ bv,
    const float* __restrict__ Wo, const float* __restrict__ bo,
    const float* __restrict__ Wat, const float* __restrict__ bat,
    const float* __restrict__ Wpy, const float* __restrict__ bpy,
    const float* __restrict__ hurst,
    const float* __restrict__ lng, const float* __restrict__ lnb,
    const float* __restrict__ Wcrop, const float* __restrict__ bcrop,
    const float* __restrict__ Wpn, const float* __restrict__ bpn,
    float* __restrict__ out)
{
  extern __shared__ __align__(16) char smem[];
  // attention aliases (R6 map)
  u16* sAin = (u16*)smem;
  u16* ctxb = (u16*)smem;
  u16* xz   = (u16*)(smem + 18432);
  u16* sVT  = (u16*)(smem + 18432);
  u16* sOut = (u16*)(smem + 18432);
  u16* sP   = (u16*)(smem + 22784);
  u16* FT   = (u16*)(smem + 28672);
  u16* sQ   = (u16*)(smem + 28672);
  u16* sK   = (u16*)(smem + 34816);
  const u16* zslot = (const u16*)(smem + 128);
  // scan aliases
  float* sX  = (float*)(smem + 2752);    // [2752,12992) pitch 20
  float* sKt = (float*)(smem + 12992);   // [12992,15488) 12*52
  float* sH  = (float*)(smem + 15488);   // [15488,15744)
  float* sM  = (float*)(smem + 15744);
  float* sS  = (float*)(smem + 15952);
  float* sU  = (float*)(smem + 16160);   // ends 16368
  float* sInn7 = (float*)(smem + 33792); // [33792,37376) 896 f32
  float* sSt7  = (float*)(smem + 37376); // [37376,40960) 896 f32

  const int tid = threadIdx.x;
  const int lane = tid & 63;
  const int w = tid >> 6;
  const int b = blockIdx.x;
  const int scanw = b & 3;

  if (w == scanw) {
    // =================== SCAN (R1-style body, x7-packed outputs) ===========
    for (int e = lane; e < 128*17; e += 64) {
      int t = e / 17; int i2 = e - t*17;
      sX[t*20 + i2] = xg[b*2176 + e];
    }
    if (lane < 52) sM[lane] = (lane < 49 && (lane % 8) == 0) ? 1.f : 0.f;
    sH[lane] = 0.f;
    WSYNC();

    float As[49];
    #pragma unroll
    for (int j = 0; j < 49; j++) As[j] = rfl(A[j]);

    float Wcb[17];
    float bcomb;
    {
      float acc[17];
      #pragma unroll
      for (int i2 = 0; i2 < 17; i2++) acc[i2] = 0.f;
      float bc = 0.f;
      #pragma unroll 4
      for (int p = 0; p < 64; p++) {
        float wt = W_exec[p*64 + lane];
        bc += b_in[p]*wt;
        #pragma unroll
        for (int i2 = 0; i2 < 17; i2++) acc[i2] += W_in[i2*64 + p]*wt;
      }
      #pragma unroll
      for (int i2 = 0; i2 < 17; i2++) Wcb[i2] = acc[i2];
      bcomb = bc + b_exec[lane];
    }
    float Wbot[64];
    #pragma unroll
    for (int i2 = 0; i2 < 64; i2++) Wbot[i2] = W_exec[(71 + i2)*64 + lane];
    float Wt7[7];
    {
      float Wmid[7];
      #pragma unroll
      for (int s = 0; s < 7; s++) Wmid[s] = W_exec[(64 + s)*64 + lane];
      #pragma unroll
      for (int j = 0; j < 7; j++) {
        float a = 0.f;
        #pragma unroll
        for (int s = 0; s < 7; s++) a += Wmid[s]*As[s*7 + j];
        Wt7[j] = a;
      }
    }
    const int si = lane >> 3, u = lane & 7;
    const int ssx = (si < 7) ? si : 0;
    float Wm8[8];
    #pragma unroll
    for (int i2 = 0; i2 < 8; i2++) {
      float wv = W_meas[(u*8 + i2)*7 + ssx];
      Wm8[i2] = (si < 7) ? wv : 0.f;
    }
    const float bm = (si < 7 && u == 0) ? b_meas[ssx] : 0.f;
    float Arow[7];
    #pragma unroll
    for (int j = 0; j < 7; j++) Arow[j] = As[ssx*7 + j];

    // Riccati (verbatim)
    {
      const int i = si, l2 = lane & 7;
      const bool valid = (i < 7) && (l2 < 7);
      const int ii = (i < 7) ? i : 0, ll = (l2 < 7) ? l2 : 0;
      float Ai[7], Al[7];
      #pragma unroll
      for (int j = 0; j < 7; j++) { Ai[j] = As[ii*7 + j]; Al[j] = As[ll*7 + j]; }
      for (int t = 0; t < 12; t++) {
        float Mf[49];
        #pragma unroll
        for (int q = 0; q < 12; q++) { float4 mv = ((const float4*)sM)[q];
          Mf[4*q] = mv.x; Mf[4*q+1] = mv.y; Mf[4*q+2] = mv.z; Mf[4*q+3] = mv.w; }
        Mf[48] = sM[48];
        const float pd = (t == 0) ? 0.1f : 0.5f;
        const float pm = (t == 0) ? 0.f  : -0.25f;
        float pp = 0.f;
        #pragma unroll
        for (int k = 0; k < 7; k++) {
          float md = 0.f;
          #pragma unroll
          for (int j = 0; j < 7; j++) md += Ai[j]*Mf[j*7 + k];
          pp += (pd*Ai[k] + pm*md)*Al[k];
        }
        float S_own = pp + ((i == l2) ? 1.f : 0.f);
        WSYNC();
        if (valid) sS[i*7 + l2] = S_own;
        WSYNC();
        float Srow[7], Mrow[7], Mcol[7], Mown;
        #pragma unroll
        for (int k = 0; k < 7; k++) { Srow[k] = sS[ii*7 + k]; Mrow[k] = sM[ii*7 + k]; Mcol[k] = sM[k*7 + ll]; }
        Mown = sM[ii*7 + ll];
        for (int it = 0; it < 3; it++) {
          float Uo = 0.f;
          #pragma unroll
          for (int k = 0; k < 7; k++) Uo += Srow[k]*Mcol[k];
          WSYNC();
          if (valid) sU[i*7 + l2] = Uo;
          WSYNC();
          float d = 0.f;
          #pragma unroll
          for (int k = 0; k < 7; k++) d += Mrow[k]*sU[k*7 + ll];
          float Mn = 2.f*Mown - d;
          WSYNC();
          if (valid) sM[i*7 + l2] = Mn;
          WSYNC();
          if (it < 2) {
            #pragma unroll
            for (int k = 0; k < 7; k++) { Mrow[k] = sM[ii*7 + k]; Mcol[k] = sM[k*7 + ll]; }
            Mown = Mn;
          }
        }
        if (lane < 49)
          sKt[t*52 + lane] = (((lane % 8) == 0) ? 1.f : 0.f) - 0.5f*sM[lane];
        else if (lane < 52)
          sKt[t*52 + lane] = 0.f;
      }
    }
    WSYNC();
    if (lane == 0) {
      float tr = 0.f;
      #pragma unroll
      for (int s = 0; s < 7; s++) tr += 0.5f*(1.f - 0.5f*sM[s*8]);
      out[O_UNC + b] = oclamp(tr);
    }
    float Kf7[7];
    #pragma unroll
    for (int j = 0; j < 7; j++) Kf7[j] = sKt[11*52 + ssx*7 + j];

    float xs[7];
    #pragma unroll
    for (int s = 0; s < 7; s++) xs[s] = 0.f;
    float g0 = 0.f, g1 = 0.f, g2 = 0.f, g3 = 0.f;
    float preX = bcomb;
    #pragma unroll
    for (int i2 = 0; i2 < 17; i2++) preX += sX[i2]*Wcb[i2];

    #define SCAN_STEP(T)                                                      \
    {                                                                         \
      float xpo = 0.f;                                                        \
      _Pragma("unroll")                                                       \
      for (int j = 0; j < 7; j++) xpo += Arow[j]*xs[j];                       \
      float preXn = bcomb;                                                    \
      if ((T) < 127) {                                                        \
        const float4* xp4 = (const float4*)(sX + ((T)+1)*20);                 \
        float4 xa = xp4[0], xb = xp4[1], xc = xp4[2], xd = xp4[3];            \
        float xe = sX[((T)+1)*20 + 16];                                       \
        preXn += xa.x*Wcb[0];  preXn += xa.y*Wcb[1];                          \
        preXn += xa.z*Wcb[2];  preXn += xa.w*Wcb[3];                          \
        preXn += xb.x*Wcb[4];  preXn += xb.y*Wcb[5];                          \
        preXn += xb.z*Wcb[6];  preXn += xb.w*Wcb[7];                          \
        preXn += xc.x*Wcb[8];  preXn += xc.y*Wcb[9];                          \
        preXn += xc.z*Wcb[10]; preXn += xc.w*Wcb[11];                         \
        preXn += xd.x*Wcb[12]; preXn += xd.y*Wcb[13];                         \
        preXn += xd.z*Wcb[14]; preXn += xd.w*Wcb[15];                         \
        preXn += xe*Wcb[16];                                                  \
      }                                                                       \
      float pre = preX;                                                       \
      _Pragma("unroll")                                                       \
      for (int j = 0; j < 7; j++) pre += Wt7[j]*xs[j];                        \
      pre += (g0 + g1) + (g2 + g3);                                           \
      float ex = __expf(2.f*pre);                                             \
      float hn = 1.f - 2.f/(ex + 1.f);                                        \
      sH[lane] = hn;                                                          \
      float4 v0 = ((const float4*)(sH + u*8))[0];                             \
      float4 v1 = ((const float4*)(sH + u*8))[1];                             \
      float4 hq[16];                                                          \
      _Pragma("unroll")                                                       \
      for (int q = 0; q < 16; q++) hq[q] = ((const float4*)sH)[q];            \
      keep4(v0); keep4(v1);                                                   \
      _Pragma("unroll")                                                       \
      for (int q = 0; q < 16; q++) keep4(hq[q]);                              \
      __builtin_amdgcn_sched_barrier(0);                                      \
      float part = v0.x*Wm8[0] + v0.y*Wm8[1] + v0.z*Wm8[2] + v0.w*Wm8[3]      \
                 + v1.x*Wm8[4] + v1.y*Wm8[5] + v1.z*Wm8[6] + v1.w*Wm8[7] + bm;\
      part = DPPADD(part, 0xB1);                                              \
      part = DPPADD(part, 0x4E);                                              \
      part = DPPADD(part, 0x141);                                             \
      float inn = part - xpo;                                                 \
      if (u == 0 && si < 7) sInn7[(T)*7 + si] = inn;                          \
      float ir[7];                                                            \
      _Pragma("unroll")                                                       \
      for (int j = 0; j < 7; j++) ir[j] = rlane(inn, j*8);                    \
      float aown = xpo;                                                       \
      _Pragma("unroll")                                                       \
      for (int j = 0; j < 7; j++) aown += Krw[j]*ir[j];                       \
      _Pragma("unroll")                                                       \
      for (int s = 0; s < 7; s++) xs[s] = rlane(aown, s*8);                   \
      if (u == 0 && si < 7) sSt7[(T)*7 + si] = aown;                          \
      g0 = 0.f; g1 = 0.f; g2 = 0.f; g3 = 0.f;                                 \
      _Pragma("unroll")                                                       \
      for (int q = 0; q < 16; q++) {                                          \
        g0 += hq[q].x*Wbot[4*q+0]; g1 += hq[q].y*Wbot[4*q+1];                 \
        g2 += hq[q].z*Wbot[4*q+2]; g3 += hq[q].w*Wbot[4*q+3];                 \
      }                                                                       \
      preX = preXn;                                                           \
    }

    for (int t = 0; t < 12; t++) {
      float Krw[7];
      #pragma unroll
      for (int j = 0; j < 7; j++) Krw[j] = sKt[t*52 + ssx*7 + j];
      SCAN_STEP(t)
    }
    {
      float Krw[7];
      #pragma unroll
      for (int j = 0; j < 7; j++) Krw[j] = Kf7[j];
      for (int t = 12; t < 128; t++) {
        SCAN_STEP(t)
      }
    }
    #undef SCAN_STEP
  } else {
    // ============== PREWORK by the 3 non-scan waves (scan's shadow) ========
    int o = (w > scanw) ? (w - 1) : w;   // ordinal 0..2
    if (o == 0) {
      PAD_F(smem, 1 + (lane >> 2), lane & 3) = 0.f;       // pooled acc
    } else if (o == 1) {
      if (lane == 0) PAD_F(smem, 18, 0) = 0.f;            // energy
      else if (lane == 1) { int4 z = {0,0,0,0}; *(int4*)(smem + 128) = z; }
    }
    // xz: all cols except 18-24 (state filled post-scan)
    for (int e = o*64 + lane; e < 5120; e += 192) {
      int t = e / 40, c = e - t*40;
      if (c >= 18 && c < 25) continue;
      float v = 0.f;
      if (c < 17) v = xg[b*2176 + t*17 + c];
      else if (c == 17) v = 1.0f;
      xz[e] = f2us(v);
    }
    // phase B: FT = [W_in;b_in;0] @ W_attn[0:64]; tiles idx%3==o
    for (int idx = o; idx < 8; idx += 3) {
      int mt = idx >> 2, nt = idx & 3;
      bfrag a0 = ldInG(W_in, b_in, mt*16, 0);
      bfrag a1 = ldInG(W_in, b_in, mt*16, 32);
      bfrag b0 = ldWG(Wat, nt*16, 0);
      bfrag b1 = ldWG(Wat, nt*16, 32);
      ffrag c = {0.f,0.f,0.f,0.f};
      c = MFMA16(a0, b0, c);
      c = MFMA16(a1, b1, c);
      stfragT(FT, mt*16, nt*16, 40, c);
    }
  }
  __syncthreads();                                         // SYNC1: scan done

  // ---- energy (values == old global round-trip: oclamp'd) ----
  {
    float ss2 = 0.f;
    for (int e = tid; e < 896; e += 256) {
      float iv = oclamp(sInn7[e]);
      ss2 += iv*iv;
    }
    ss2 += __shfl_xor(ss2, 1);  ss2 += __shfl_xor(ss2, 2);
    ss2 += __shfl_xor(ss2, 4);  ss2 += __shfl_xor(ss2, 8);
    ss2 += __shfl_xor(ss2, 16); ss2 += __shfl_xor(ss2, 32);
    if (lane == 0) atomicAdd(&PAD_F(smem, 18, 0), ss2);
  }
  // ---- xz state cols 18-24 ----
  for (int i = tid; i < 896; i += 256) {
    int t = i / 7, s = i - t*7;
    xz[t*40 + 18 + s] = f2us(oclamp(sSt7[i]));
  }
  // ---- FT tail (overwrites B's zero rows 18-24; B visible via SYNC1) ----
  for (int e = tid; e < 448; e += 256) {
    int s = e >> 6, n = e & 63;
    FT[n*40 + 18 + s] = f2us(Wat[(64 + s)*64 + n]);
  }
  // ---- bulk global stores (innov/state/xfin) ----
  for (int e = tid; e < 896; e += 256) {
    out[O_INNOV + b*896 + e] = oclamp(sInn7[e]);
    out[O_STATE + b*896 + e] = oclamp(sSt7[e]);
  }
  if (tid < 7) out[O_XFIN + b*7 + tid] = oclamp(sSt7[127*7 + tid]);
  __syncthreads();                                         // SYNC2
  if (tid < 4) {
    float ch = fminf(PAD_F(smem, 18, 0)*(1.f/896.f), 10.f)*0.1f;
    float g = ch*Wpy[tid] + hurst[b]*Wpy[4 + tid] + bpy[tid];
    PAD_F(smem, 17, tid) = 1.f/(1.f + __expf(-g));
  }
  // ---- phase C: Ain = xz @ FT^T + bat -> sAin ----
  #pragma unroll
  for (int mt = 0; mt < 2; mt++) {
    int r0 = w*32 + mt*16;
    bfrag a = ldfrag(xz, r0, 40, 0);
    #pragma unroll
    for (int nt = 0; nt < 4; nt++) {
      bfrag bf = ldfrag(FT, nt*16, 40, 0);
      ffrag c = {0.f,0.f,0.f,0.f};
      c = MFMA16(a, bf, c);
      c += bat[nt*16 + (lane & 15)];
      stfrag(sAin, r0, nt*16, 72, c);
    }
  }
  __syncthreads();                                         // S4

  // ---- heads (verbatim R6) ----
  ffrag ctxr[4][2];
  for (int h = 0; h < 4; h++) {
    bfrag bq0 = ldWG(Wq, 16*h, 0), bq1 = ldWG(Wq, 16*h, 32);
    bfrag bk0 = ldWG(Wk, 16*h, 0), bk1 = ldWG(Wk, 16*h, 32);
    bfrag bv0 = ldWG(Wv, 16*h, 0), bv1 = ldWG(Wv, 16*h, 32);
    #pragma unroll
    for (int mt = 0; mt < 2; mt++) {
      int r0 = w*32 + mt*16;
      bfrag a0 = ldfrag(sAin, r0, 72, 0);
      bfrag a1 = ldfrag(sAin, r0, 72, 32);
      {
        ffrag c = {0.f,0.f,0.f,0.f};
        c = MFMA16(a0, bq0, c); c = MFMA16(a1, bq1, c);
        c += bq[16*h + (lane & 15)];
        stfrag(sQ, r0, 0, 24, c);
      }
      {
        ffrag c = {0.f,0.f,0.f,0.f};
        c = MFMA16(a0, bk0, c); c = MFMA16(a1, bk1, c);
        c += bk[16*h + (lane & 15)];
        stfrag(sK, r0, 0, 24, c);
      }
      {
        ffrag c = {0.f,0.f,0.f,0.f};
        c = MFMA16(a0, bv0, c); c = MFMA16(a1, bv1, c);
        c += bv[16*h + (lane & 15)];
        stfragT(sVT, r0, 0, 136, c);
      }
    }
    __syncthreads();                                       // Sh1
    float scale = 0.25f*PAD_F(smem, 17, h);
    bfrag qa0 = ldQK(sQ, zslot, w*32);
    bfrag qa1 = ldQK(sQ, zslot, w*32 + 16);
    ffrag sc[2][8];
    #pragma unroll
    for (int nt = 0; nt < 8; nt++) {
      bfrag kb = ldQK(sK, zslot, nt*16);
      ffrag z0 = {0.f,0.f,0.f,0.f};
      ffrag z1 = {0.f,0.f,0.f,0.f};
      sc[0][nt] = MFMA16(qa0, kb, z0);
      sc[1][nt] = MFMA16(qa1, kb, z1);
    }
    __syncthreads();                                       // Sh2
    u16* sPw = sP + w*2176;
    #pragma unroll
    for (int mt = 0; mt < 2; mt++) {
      #pragma unroll
      for (int nt = 0; nt < 8; nt++) sc[mt][nt] *= scale;
      float mx[4], sum[4];
      #pragma unroll
      for (int r = 0; r < 4; r++) {
        float m_ = sc[mt][0][r];
        #pragma unroll
        for (int nt = 1; nt < 8; nt++) m_ = fmaxf(m_, sc[mt][nt][r]);
        m_ = DPPMAX(m_, 0xB1);
        m_ = DPPMAX(m_, 0x4E);
        m_ = DPPMAX(m_, 0x141);
        m_ = DPPMAX(m_, 0x128);
        mx[r] = m_; sum[r] = 0.f;
      }
      #pragma unroll
      for (int nt = 0; nt < 8; nt++) {
        #pragma unroll
        for (int r = 0; r < 4; r++) {
          float p = __expf(sc[mt][nt][r] - mx[r]);
          sc[mt][nt][r] = p; sum[r] += p;
        }
      }
      #pragma unroll
      for (int r = 0; r < 4; r++) {
        float s_ = sum[r];
        s_ = DPPADD(s_, 0xB1);
        s_ = DPPADD(s_, 0x4E);
        s_ = DPPADD(s_, 0x141);
        s_ = DPPADD(s_, 0x128);
        sum[r] = 1.f/s_;
      }
      int rb = (lane >> 4) << 2;
      int cb = lane & 15;
      #pragma unroll
      for (int nt = 0; nt < 8; nt++) {
        #pragma unroll
        for (int r = 0; r < 4; r++)
          sPw[(rb + r)*136 + nt*16 + cb] = f2us(sc[mt][nt][r]*sum[r]);
      }
      ffrag cc = {0.f,0.f,0.f,0.f};
      #pragma unroll
      for (int ks = 0; ks < 4; ks++) {
        bfrag pa = ldfrag(sPw, 0, 136, ks*32);
        bfrag vb = ldfrag(sVT, 0, 136, ks*32);
        cc = MFMA16(pa, vb, cc);
      }
      ctxr[h][mt] = cc;
    }
    __syncthreads();                                       // Sh3
  }
  // ---- ctx -> ctxb; Wo -> sOut + pooled; pheno; crop (verbatim R6) ----
  #pragma unroll
  for (int h = 0; h < 4; h++)
    #pragma unroll
    for (int mt = 0; mt < 2; mt++)
      stfrag(ctxb, w*32 + mt*16, 16*h, 72, ctxr[h][mt]);
  float pacc[4];
  {
    bfrag a00 = ldfrag(ctxb, w*32, 72, 0);
    bfrag a01 = ldfrag(ctxb, w*32, 72, 32);
    bfrag a10 = ldfrag(ctxb, w*32 + 16, 72, 0);
    bfrag a11 = ldfrag(ctxb, w*32 + 16, 72, 32);
    #pragma unroll
    for (int nt = 0; nt < 4; nt++) {
      bfrag b0 = ldWG(Wo, nt*16, 0);
      bfrag b1 = ldWG(Wo, nt*16, 32);
      ffrag c0 = {0.f,0.f,0.f,0.f};
      ffrag c1 = {0.f,0.f,0.f,0.f};
      c0 = MFMA16(a00, b0, c0); c0 = MFMA16(a01, b1, c0);
      c1 = MFMA16(a10, b0, c1); c1 = MFMA16(a11, b1, c1);
      float bn = bo[nt*16 + (lane & 15)];
      c0 += bn; c1 += bn;
      pacc[nt] = c0[0]+c0[1]+c0[2]+c0[3]+c1[0]+c1[1]+c1[2]+c1[3];
      stfrag(sOut, w*32, nt*16, 72, c0);
      stfrag(sOut, w*32 + 16, nt*16, 72, c1);
    }
  }
  #pragma unroll
  for (int nt = 0; nt < 4; nt++) {
    pacc[nt] += __shfl_xor(pacc[nt], 16);
    pacc[nt] += __shfl_xor(pacc[nt], 32);
    if ((lane >> 4) == 0) {
      int j = nt*16 + (lane & 15);
      atomicAdd(&PAD_F(smem, 1 + (j >> 2), j & 3), pacc[nt]);
    }
  }
  __syncthreads();                                         // S5
  {
    int col = lane & 15;
    float bn = (col < 7) ? bpn[col] : 0.f;
    bfrag b0 = ldPnG(Wpn, 0);
    bfrag b1 = ldPnG(Wpn, 32);
    #pragma unroll
    for (int mt = 0; mt < 2; mt++) {
      bfrag a0 = ldfrag(sOut, w*32 + mt*16, 72, 0);
      bfrag a1 = ldfrag(sOut, w*32 + mt*16, 72, 32);
      ffrag c = {0.f,0.f,0.f,0.f};
      c = MFMA16(a0, b0, c);
      c = MFMA16(a1, b1, c);
      c += bn;
      if (col < 7) {
        int m0 = w*32 + mt*16 + ((lane >> 4) << 2);
        #pragma unroll
        for (int r = 0; r < 4; r++)
          out[O_PHENO + (b*128 + m0 + r)*7 + col] = oclamp(c[r]);
      }
    }
  }
  if (w == 0) {
    float p = PAD_F(smem, 1 + (lane >> 2), lane & 3)*(1.f/128.f);
    float mu = p;
    mu += __shfl_xor(mu, 1); mu += __shfl_xor(mu, 2); mu += __shfl_xor(mu, 4);
    mu += __shfl_xor(mu, 8); mu += __shfl_xor(mu, 16); mu += __shfl_xor(mu, 32);
    mu *= (1.f/64.f);
    float e_ = p - mu;
    float vv = e_*e_;
    vv += __shfl_xor(vv, 1); vv += __shfl_xor(vv, 2); vv += __shfl_xor(vv, 4);
    vv += __shfl_xor(vv, 8); vv += __shfl_xor(vv, 16); vv += __shfl_xor(vv, 32);
    vv *= (1.f/64.f);
    float y = e_*rsqrtf(vv + 1e-5f)*lng[lane] + lnb[lane];
    #pragma unroll
    for (int c = 0; c < 3; c++) {
      float t_ = y*Wcrop[lane*3 + c];
      t_ += __shfl_xor(t_, 1); t_ += __shfl_xor(t_, 2); t_ += __shfl_xor(t_, 4);
      t_ += __shfl_xor(t_, 8); t_ += __shfl_xor(t_, 16); t_ += __shfl_xor(t_, 32);
      if (lane == 0) out[O_CROP + b*3 + c] = oclamp(t_ + bcrop[c]);
    }
  }
}

extern "C" void kernel_launch(void* const* d_in, const int* in_sizes, int n_in,
                              void* d_out, int out_size, void* d_ws, size_t ws_size,
                              hipStream_t stream) {
  const float* xg     = (const float*)d_in[0];
  const float* hurst  = (const float*)d_in[2];
  const float* W_in   = (const float*)d_in[3];
  const float* b_in   = (const float*)d_in[4];
  const float* W_exec = (const float*)d_in[5];
  const float* b_exec = (const float*)d_in[6];
  const float* W_meas = (const float*)d_in[7];
  const float* b_meas = (const float*)d_in[8];
  const float* Amat   = (const float*)d_in[9];
  const float* W_attn = (const float*)d_in[10];
  const float* b_attn = (const float*)d_in[11];
  const float* Wq  = (const float*)d_in[12];
  const float* bqp = (const float*)d_in[13];
  const float* Wk  = (const float*)d_in[14];
  const float* bkp = (const float*)d_in[15];
  const float* Wv  = (const float*)d_in[16];
  const float* bvp = (const float*)d_in[17];
  const float* Wo  = (const float*)d_in[18];
  const float* bop = (const float*)d_in[19];
  const float* Wpy = (const float*)d_in[20];
  const float* bpy = (const float*)d_in[21];
  const float* lng = (const float*)d_in[22];
  const float* lnb = (const float*)d_in[23];
  const float* Wcrop = (const float*)d_in[24];
  const float* bcrop = (const float*)d_in[25];
  const float* Wpn = (const float*)d_in[26];
  const float* bpn = (const float*)d_in[27];
  float* out = (float*)d_out;
  const int SMEM = 40960;   // 4 blocks/CU exactly; all 1024 blocks resident
  hipFuncSetAttribute((const void*)k_fused, hipFuncAttributeMaxDynamicSharedMemorySize, SMEM);
  k_fused<<<1024, 256, SMEM, stream>>>(xg, W_in, b_in, W_exec, b_exec,
                                       W_meas, b_meas, Amat,
                                       Wq, bqp, Wk, bkp, Wv, bvp, Wo, bop,
                                       W_attn, b_attn, Wpy, bpy, hurst,
                                       lng, lnb, Wcrop, bcrop, Wpn, bpn, out);
}

// Round 8
// 281.537 us; speedup vs baseline: 4.0776x; 4.0776x over previous
//
#include <hip/hip_runtime.h>
#include <hip/hip_bf16.h>

// DynamisCropClassifier: Kalman-scan + gated attention classifier.
// ROUND 14: fusion (R13) REVERTED — launch_bounds(256,4) unified-file cap
//   forced a 64/64 VGPR/AGPR split; scan spilled Wbot to scratch (FETCH 11->124MB,
//   dur 1148us). Back to two kernels (R12 structure, 279.6us best known).
//   k_scan NEW: the 18 h-broadcast ds_read_b128 now live inside ONE inline-asm
//   block ending in a single s_waitcnt lgkmcnt(0) — the compiler cannot split
//   this into serial load/wait pairs (R1/R3/R6 pin attempts all failed:
//   VGPR stayed ~112). 18 early-clobber f32x4 outputs force 72 result VGPRs
//   live -> tripwire: VGPR_Count must jump to >=170. LDS byte address =
//   truncated flat pointer (LDS aperture is 4GiB-aligned on gfx9+; LLVM
//   lowers flat->LDS addrspacecast as trunc). "memory" clobber orders the
//   sH store before the asm (same-wave DS in-order). Consumers use the asm
//   outputs -> true deps, identical FMA chains -> bit-exact.
//   k_attn: verbatim R12 (4 blocks/CU, 40960B LDS diet, passing).

typedef unsigned short u16;
typedef __attribute__((ext_vector_type(8))) short bfrag;   // 8 x bf16 (4 VGPR)
typedef __attribute__((ext_vector_type(4))) float ffrag;   // 4 x f32 acc
typedef __attribute__((ext_vector_type(4))) float f32x4;   // 4 x f32 (4 VGPR)

#define MFMA16(a,b,c) __builtin_amdgcn_mfma_f32_16x16x32_bf16((a),(b),(c),0,0,0)
#define WSYNC() __builtin_amdgcn_wave_barrier()

// ---- output element offsets (fp32 elements) ----
#define O_CROP  0
#define O_PHENO 3072
#define O_INNOV 920576
#define O_UNC   1838080
#define O_XFIN  1839104
#define O_STATE 1846272

static __device__ __forceinline__ float i2f(int i){union{int i;float f;}u;u.i=i;return u.f;}
static __device__ __forceinline__ int f2i(float f){union{int i;float f;}u;u.f=f;return u.i;}
// DPP cross-lane add/max (VALU-speed, no LDS pipe).
#define DPPADD(v,ctrl) ((v) + i2f(__builtin_amdgcn_update_dpp(0, f2i(v), (ctrl), 0xF, 0xF, true)))
#define DPPMAX(v,ctrl) fmaxf((v), i2f(__builtin_amdgcn_update_dpp(0, f2i(v), (ctrl), 0xF, 0xF, true)))

static __device__ __forceinline__ u16 f2us(float f) {   // RNE fp32 -> bf16 bits
  union { float f; unsigned int i; } v; v.f = f;
  unsigned int r = v.i + 0x7FFFu + ((v.i >> 16) & 1u);
  return (u16)(r >> 16);
}
static __device__ __forceinline__ float oclamp(float v) {  // NaN-scrub diagnostic
  v = fmaxf(v, -1.0e30f); v = fminf(v, 1.0e30f); return v;
}
static __device__ __forceinline__ float rfl(float x) {     // wave-uniform -> SGPR
  return i2f(__builtin_amdgcn_readfirstlane(f2i(x)));
}
static __device__ __forceinline__ float rlane(float x, int l) {
  return i2f(__builtin_amdgcn_readlane(f2i(x), l));
}

// ============================ kernel 1: scan ============================
// One wave per batch element; wave-synchronous LDS (no s_barrier).
__global__ __launch_bounds__(64, 1) void k_scan(
    const float* __restrict__ xg,
    const float* __restrict__ W_in, const float* __restrict__ b_in,
    const float* __restrict__ W_exec, const float* __restrict__ b_exec,
    const float* __restrict__ W_meas, const float* __restrict__ b_meas,
    const float* __restrict__ A, float* __restrict__ out)
{
  __shared__ __align__(16) float sX[128*20];   // x[b], pitch 20
  __shared__ __align__(16) float sKt[12*52];   // K_t (t<12; frozen = row 11 after)
  __shared__ __align__(16) float sH[64];
  __shared__ __align__(16) float sInn[128*8];
  __shared__ __align__(16) float sSt[128*8];
  __shared__ __align__(16) float sM[52];
  __shared__ __align__(16) float sS[52];
  __shared__ __align__(16) float sU[52];
  const int lane = threadIdx.x;
  const int b = blockIdx.x;
  for (int e = lane; e < 128*17; e += 64) {
    int t = e / 17; int i2 = e - t*17;
    sX[t*20 + i2] = xg[b*2176 + e];
  }
  if (lane < 52) sM[lane] = (lane < 49 && (lane % 8) == 0) ? 1.f : 0.f;
  sH[lane] = 0.f;
  WSYNC();

  // A into SGPRs (wave-uniform) -- identical to round-6 passing kernel
  float As[49];
  #pragma unroll
  for (int j = 0; j < 49; j++) As[j] = rfl(A[j]);

  // fold: Wcb = W_in @ W_exec[0:64] (column `lane`)  [verbatim]
  float Wcb[17];
  float bcomb;
  {
    float acc[17];
    #pragma unroll
    for (int i2 = 0; i2 < 17; i2++) acc[i2] = 0.f;
    float bc = 0.f;
    #pragma unroll 4
    for (int p = 0; p < 64; p++) {
      float wt = W_exec[p*64 + lane];
      bc += b_in[p]*wt;
      #pragma unroll
      for (int i2 = 0; i2 < 17; i2++) acc[i2] += W_in[i2*64 + p]*wt;
    }
    #pragma unroll
    for (int i2 = 0; i2 < 17; i2++) Wcb[i2] = acc[i2];
    bcomb = bc + b_exec[lane];
  }
  float Wbot[64];
  #pragma unroll
  for (int i2 = 0; i2 < 64; i2++) Wbot[i2] = W_exec[(71 + i2)*64 + lane];
  float Wt7[7];                                // (A^T Wmid)  [verbatim]
  {
    float Wmid[7];
    #pragma unroll
    for (int s = 0; s < 7; s++) Wmid[s] = W_exec[(64 + s)*64 + lane];
    #pragma unroll
    for (int j = 0; j < 7; j++) {
      float a = 0.f;
      #pragma unroll
      for (int s = 0; s < 7; s++) a += Wmid[s]*As[s*7 + j];
      Wt7[j] = a;
    }
  }
  const int si = lane >> 3, u = lane & 7;
  const int ssx = (si < 7) ? si : 0;
  float Wm8[8];
  #pragma unroll
  for (int i2 = 0; i2 < 8; i2++) {
    float wv = W_meas[(u*8 + i2)*7 + ssx];
    Wm8[i2] = (si < 7) ? wv : 0.f;
  }
  const float bm = (si < 7 && u == 0) ? b_meas[ssx] : 0.f;
  // own A-row: same expression as round-6's xp[si]
  float Arow[7];
  #pragma unroll
  for (int j = 0; j < 7; j++) Arow[j] = As[ssx*7 + j];

  // ---- Riccati (12 iters; verbatim)
  {
    const int i = si, l2 = lane & 7;
    const bool valid = (i < 7) && (l2 < 7);
    const int ii = (i < 7) ? i : 0, ll = (l2 < 7) ? l2 : 0;
    float Ai[7], Al[7];
    #pragma unroll
    for (int j = 0; j < 7; j++) { Ai[j] = As[ii*7 + j]; Al[j] = As[ll*7 + j]; }
    for (int t = 0; t < 12; t++) {
      float Mf[49];
      #pragma unroll
      for (int q = 0; q < 12; q++) { float4 mv = ((const float4*)sM)[q];
        Mf[4*q] = mv.x; Mf[4*q+1] = mv.y; Mf[4*q+2] = mv.z; Mf[4*q+3] = mv.w; }
      Mf[48] = sM[48];
      const float pd = (t == 0) ? 0.1f : 0.5f;
      const float pm = (t == 0) ? 0.f  : -0.25f;
      float pp = 0.f;
      #pragma unroll
      for (int k = 0; k < 7; k++) {
        float md = 0.f;
        #pragma unroll
        for (int j = 0; j < 7; j++) md += Ai[j]*Mf[j*7 + k];
        pp += (pd*Ai[k] + pm*md)*Al[k];
      }
      float S_own = pp + ((i == l2) ? 1.f : 0.f);
      WSYNC();
      if (valid) sS[i*7 + l2] = S_own;
      WSYNC();
      float Srow[7], Mrow[7], Mcol[7], Mown;
      #pragma unroll
      for (int k = 0; k < 7; k++) { Srow[k] = sS[ii*7 + k]; Mrow[k] = sM[ii*7 + k]; Mcol[k] = sM[k*7 + ll]; }
      Mown = sM[ii*7 + ll];
      for (int it = 0; it < 3; it++) {           // Newton: M' = 2M - M S M
        float Uo = 0.f;
        #pragma unroll
        for (int k = 0; k < 7; k++) Uo += Srow[k]*Mcol[k];
        WSYNC();
        if (valid) sU[i*7 + l2] = Uo;
        WSYNC();
        float d = 0.f;
        #pragma unroll
        for (int k = 0; k < 7; k++) d += Mrow[k]*sU[k*7 + ll];
        float Mn = 2.f*Mown - d;
        WSYNC();
        if (valid) sM[i*7 + l2] = Mn;
        WSYNC();
        if (it < 2) {
          #pragma unroll
          for (int k = 0; k < 7; k++) { Mrow[k] = sM[ii*7 + k]; Mcol[k] = sM[k*7 + ll]; }
          Mown = Mn;
        }
      }
      if (lane < 49)
        sKt[t*52 + lane] = (((lane % 8) == 0) ? 1.f : 0.f) - 0.5f*sM[lane];
      else if (lane < 52)
        sKt[t*52 + lane] = 0.f;
    }
  }
  WSYNC();
  if (lane == 0) {                               // trace(P_fin) = trace(0.5 K)
    float tr = 0.f;
    #pragma unroll
    for (int s = 0; s < 7; s++) tr += 0.5f*(1.f - 0.5f*sM[s*8]);
    out[O_UNC + b] = oclamp(tr);
  }
  // frozen K own-row (values == round-6's Kreg[si*7+j] after t=11)
  float Kf7[7];
  #pragma unroll
  for (int j = 0; j < 7; j++) Kf7[j] = sKt[11*52 + ssx*7 + j];

  // ---- 128-step scan (bit-exact round-6 arithmetic; asm-batched h reads) ----
  float xs[7];
  #pragma unroll
  for (int s = 0; s < 7; s++) xs[s] = 0.f;
  float g0 = 0.f, g1 = 0.f, g2 = 0.f, g3 = 0.f;
  float preX = bcomb;
  #pragma unroll
  for (int i2 = 0; i2 < 17; i2++) preX += sX[i2]*Wcb[i2];

  // LDS byte offset of sH (flat ptr truncation; LDS aperture 4GiB-aligned)
  const unsigned hbase = (unsigned)(unsigned long long)(const void*)sH;
  const unsigned hpart = hbase + ((unsigned)u << 5);   // sH + u*8 floats

  // one step body; Krw[] must already hold this step's K own-row.
  #define SCAN_STEP(T)                                                        \
  {                                                                           \
    float xpo = 0.f;                                                          \
    _Pragma("unroll")                                                         \
    for (int j = 0; j < 7; j++) xpo += Arow[j]*xs[j];                         \
    float preXn = bcomb;                                                      \
    if ((T) < 127) {                                                          \
      const float4* xp4 = (const float4*)(sX + ((T)+1)*20);                   \
      float4 xa = xp4[0], xb = xp4[1], xc = xp4[2], xd = xp4[3];              \
      float xe = sX[((T)+1)*20 + 16];                                         \
      preXn += xa.x*Wcb[0];  preXn += xa.y*Wcb[1];                            \
      preXn += xa.z*Wcb[2];  preXn += xa.w*Wcb[3];                            \
      preXn += xb.x*Wcb[4];  preXn += xb.y*Wcb[5];                            \
      preXn += xb.z*Wcb[6];  preXn += xb.w*Wcb[7];                            \
      preXn += xc.x*Wcb[8];  preXn += xc.y*Wcb[9];                            \
      preXn += xc.z*Wcb[10]; preXn += xc.w*Wcb[11];                           \
      preXn += xd.x*Wcb[12]; preXn += xd.y*Wcb[13];                           \
      preXn += xd.z*Wcb[14]; preXn += xd.w*Wcb[15];                           \
      preXn += xe*Wcb[16];                                                    \
    }                                                                         \
    float pre = preX;                                                         \
    _Pragma("unroll")                                                         \
    for (int j = 0; j < 7; j++) pre += Wt7[j]*xs[j];                          \
    pre += (g0 + g1) + (g2 + g3);                                             \
    float ex = __expf(2.f*pre);                                               \
    float hn = 1.f - 2.f/(ex + 1.f);             /* tanh, Inf-safe */         \
    sH[lane] = hn;                               /* same-wave DS in-order */  \
    /* ALL 18 h reads in ONE asm block -> single lgkm wait per step */        \
    f32x4 v0, v1, hq[16];                                                     \
    asm volatile(                                                             \
      "ds_read_b128 %0, %18\n\t"                                              \
      "ds_read_b128 %1, %18 offset:16\n\t"                                    \
      "ds_read_b128 %2, %19\n\t"                                              \
      "ds_read_b128 %3, %19 offset:16\n\t"                                    \
      "ds_read_b128 %4, %19 offset:32\n\t"                                    \
      "ds_read_b128 %5, %19 offset:48\n\t"                                    \
      "ds_read_b128 %6, %19 offset:64\n\t"                                    \
      "ds_read_b128 %7, %19 offset:80\n\t"                                    \
      "ds_read_b128 %8, %19 offset:96\n\t"                                    \
      "ds_read_b128 %9, %19 offset:112\n\t"                                   \
      "ds_read_b128 %10, %19 offset:128\n\t"                                  \
      "ds_read_b128 %11, %19 offset:144\n\t"                                  \
      "ds_read_b128 %12, %19 offset:160\n\t"                                  \
      "ds_read_b128 %13, %19 offset:176\n\t"                                  \
      "ds_read_b128 %14, %19 offset:192\n\t"                                  \
      "ds_read_b128 %15, %19 offset:208\n\t"                                  \
      "ds_read_b128 %16, %19 offset:224\n\t"                                  \
      "ds_read_b128 %17, %19 offset:240\n\t"                                  \
      "s_waitcnt lgkmcnt(0)"                                                  \
      : "=&v"(v0), "=&v"(v1),                                                 \
        "=&v"(hq[0]),  "=&v"(hq[1]),  "=&v"(hq[2]),  "=&v"(hq[3]),            \
        "=&v"(hq[4]),  "=&v"(hq[5]),  "=&v"(hq[6]),  "=&v"(hq[7]),            \
        "=&v"(hq[8]),  "=&v"(hq[9]),  "=&v"(hq[10]), "=&v"(hq[11]),           \
        "=&v"(hq[12]), "=&v"(hq[13]), "=&v"(hq[14]), "=&v"(hq[15])            \
      : "v"(hpart), "v"(hbase)                                                \
      : "memory");                                                            \
    __builtin_amdgcn_sched_barrier(0);                                        \
    /* ---- Kalman chain + GEMV on register values (no further waits) ---- */ \
    float part = v0[0]*Wm8[0] + v0[1]*Wm8[1] + v0[2]*Wm8[2] + v0[3]*Wm8[3]    \
               + v1[0]*Wm8[4] + v1[1]*Wm8[5] + v1[2]*Wm8[6] + v1[3]*Wm8[7]    \
               + bm;                                                          \
    part = DPPADD(part, 0xB1);                                                \
    part = DPPADD(part, 0x4E);                                                \
    part = DPPADD(part, 0x141);                                               \
    float inn = part - xpo;                                                   \
    if (u == 0 && si < 7) sInn[(T)*8 + si] = inn;                             \
    float ir[7];                                 /* innov -> SGPRs */         \
    _Pragma("unroll")                                                         \
    for (int j = 0; j < 7; j++) ir[j] = rlane(inn, j*8);                      \
    float aown = xpo;                                                         \
    _Pragma("unroll")                                                         \
    for (int j = 0; j < 7; j++) aown += Krw[j]*ir[j];                         \
    _Pragma("unroll")                                                         \
    for (int s = 0; s < 7; s++) xs[s] = rlane(aown, s*8);                     \
    if (u == 0 && si < 7) sSt[(T)*8 + si] = aown;                             \
    /* GEMV(h_t) for step t+1; per-accumulator order == round-6 */            \
    g0 = 0.f; g1 = 0.f; g2 = 0.f; g3 = 0.f;                                   \
    _Pragma("unroll")                                                         \
    for (int q = 0; q < 16; q++) {                                            \
      g0 += hq[q][0]*Wbot[4*q+0]; g1 += hq[q][1]*Wbot[4*q+1];                 \
      g2 += hq[q][2]*Wbot[4*q+2]; g3 += hq[q][3]*Wbot[4*q+3];                 \
    }                                                                         \
    preX = preXn;                                                             \
  }

  for (int t = 0; t < 12; t++) {                 // varying-K steps
    float Krw[7];
    #pragma unroll
    for (int j = 0; j < 7; j++) Krw[j] = sKt[t*52 + ssx*7 + j];
    SCAN_STEP(t)
  }
  {
    float Krw[7];
    #pragma unroll
    for (int j = 0; j < 7; j++) Krw[j] = Kf7[j];
    for (int t = 12; t < 128; t++) {             // frozen-K steps (hot)
      SCAN_STEP(t)
    }
  }
  #undef SCAN_STEP

  WSYNC();
  for (int e = lane; e < 896; e += 64) {         // bulk coalesced stores
    int t = e/7, s = e - t*7;
    out[O_INNOV + b*896 + e] = oclamp(sInn[t*8 + s]);
    out[O_STATE + b*896 + e] = oclamp(sSt[t*8 + s]);
  }
  if (lane < 7) out[O_XFIN + b*7 + lane] = oclamp(sSt[127*8 + lane]);
}

// ============================ kernel 2: attention ============================
static __device__ __forceinline__ bfrag ldfrag(const u16* t, int row0, int pitch, int koff) {
  int l = threadIdx.x & 63;
  return *(const bfrag*)(t + (row0 + (l & 15))*pitch + koff + ((l >> 4) << 3));
}
// Q/K fragment: groups 0-1 read data cols 0-15 (pitch 24); groups 2-3 read a
// shared 16B zero slot (same zero operand values as the old zeroed cols 16-31).
static __device__ __forceinline__ bfrag ldQK(const u16* base, const u16* zslot, int row0) {
  int l = threadIdx.x & 63;
  int g = l >> 4;
  const u16* p = (g < 2) ? (base + (row0 + (l & 15))*24 + g*8) : zslot;
  return *(const bfrag*)p;
}
static __device__ __forceinline__ void stfrag(u16* t, int row0, int col0, int pitch, ffrag d) {
  int l = threadIdx.x & 63;
  int col = col0 + (l & 15);
  int r0 = row0 + ((l >> 4) << 2);
  #pragma unroll
  for (int r = 0; r < 4; r++) t[(r0 + r)*pitch + col] = f2us(d[r]);
}
static __device__ __forceinline__ void stfragT(u16* t, int row0, int col0, int pitch, ffrag d) {
  int l = threadIdx.x & 63;
  int n = col0 + (l & 15);
  int m0 = row0 + ((l >> 4) << 2);
  ushort4 pk;
  pk.x = f2us(d[0]); pk.y = f2us(d[1]); pk.z = f2us(d[2]); pk.w = f2us(d[3]);
  *(ushort4*)(t + n*pitch + m0) = pk;
}
// --- on-the-fly global weight fragments (values == old f2us staging) ---
static __device__ __forceinline__ bfrag ldWG(const float* __restrict__ W, int n0, int koff) {
  int l = threadIdx.x & 63;
  int n = n0 + (l & 15);
  int k0 = koff + ((l >> 4) << 3);
  bfrag r;
  #pragma unroll
  for (int kk = 0; kk < 8; kk++) r[kk] = (short)f2us(W[(k0 + kk)*64 + n]);
  return r;
}
static __device__ __forceinline__ bfrag ldPnG(const float* __restrict__ Wpn, int koff) {
  int l = threadIdx.x & 63;
  int n = l & 15;
  int k0 = koff + ((l >> 4) << 3);
  bfrag r;
  #pragma unroll
  for (int kk = 0; kk < 8; kk++) {
    float v = (n < 7) ? Wpn[(k0 + kk)*7 + n] : 0.f;
    r[kk] = (short)f2us(v);
  }
  return r;
}
static __device__ __forceinline__ bfrag ldInG(const float* __restrict__ W_in,
                                              const float* __restrict__ b_in,
                                              int r0, int koff) {
  int l = threadIdx.x & 63;
  int r = r0 + (l & 15);
  int k0 = koff + ((l >> 4) << 3);
  bfrag o;
  #pragma unroll
  for (int kk = 0; kk < 8; kk++) {
    float v = 0.f;
    if (r < 17) v = W_in[r*64 + k0 + kk];
    else if (r == 17) v = b_in[k0 + kk];
    o[kk] = (short)f2us(v);
  }
  return o;
}

// scalar slot j in sAin row r's pad (bytes r*144+128 .. +144): never touched
// by any stfrag/ldfrag (cols 64-71).
#define PAD_F(smem, r, j) (((float*)((smem) + (r)*144 + 128))[j])

__global__ __launch_bounds__(256, 4) void k_attn(
    const float* __restrict__ xg,
    const float* __restrict__ Wq, const float* __restrict__ bq,
    const float* __restrict__ Wk, const float* __restrict__ bk,
    const float* __restrict__ Wv, const float* __restrict__ bv,
    const float* __restrict__ Wo, const float* __restrict__ bo,
    const float* __restrict__ W_in, const float* __restrict__ b_in,
    const float* __restrict__ Wat, const float* __restrict__ bat,
    const float* __restrict__ Wpy, const float* __restrict__ bpy,
    const float* __restrict__ hurst,
    const float* __restrict__ lng, const float* __restrict__ lnb,
    const float* __restrict__ Wcrop, const float* __restrict__ bcrop,
    const float* __restrict__ Wpn, const float* __restrict__ bpn,
    float* __restrict__ out)
{
  extern __shared__ __align__(16) char smem[];
  u16* sAin = (u16*)smem;                 // [0,18432) ; ctxb post-heads
  u16* ctxb = (u16*)smem;
  u16* xz   = (u16*)(smem + 18432);       // [18432,28672) phases A-C
  u16* sVT  = (u16*)(smem + 18432);       // heads: [18432,22784)
  u16* sOut = (u16*)(smem + 18432);       // post-heads: [18432,36864)
  u16* sP   = (u16*)(smem + 22784);       // heads post-Sh2: +w*2176 u16
  u16* FT   = (u16*)(smem + 28672);       // [28672,33792) phases B-C
  u16* sQ   = (u16*)(smem + 28672);       // heads: [28672,34816) pitch 24
  u16* sK   = (u16*)(smem + 34816);       // heads: [34816,40960) pitch 24
  const u16* zslot = (const u16*)(smem + 128);  // sAin row0 pad: 16B zeros
  const int tid = threadIdx.x;
  const int lane = tid & 63;
  const int w = tid >> 6;
  const int b = blockIdx.x;
  const float* stateg = out + O_STATE + b*896;

  // ---- phase A: staging + pad inits ----
  for (int e = tid; e < 5120; e += 256) {
    int t = e / 40, c = e - t*40;
    float v = 0.f;
    if (c < 17) v = xg[b*2176 + t*17 + c];
    else if (c == 17) v = 1.0f;
    else if (c < 25) v = stateg[t*7 + (c - 18)];
    xz[e] = f2us(v);
  }
  if (tid < 64) PAD_F(smem, 1 + (tid >> 2), tid & 3) = 0.f;   // pooled acc
  else if (tid == 80) PAD_F(smem, 18, 0) = 0.f;               // energy
  else if (tid == 81) { int4 z = {0,0,0,0}; *(int4*)(smem + 128) = z; } // zero slot
  __syncthreads();                                         // S0 (init visible)
  {
    float ss2 = 0.f;
    for (int e = tid; e < 896; e += 256) {
      float iv = out[O_INNOV + b*896 + e];
      ss2 += iv*iv;
    }
    ss2 += __shfl_xor(ss2, 1);  ss2 += __shfl_xor(ss2, 2);
    ss2 += __shfl_xor(ss2, 4);  ss2 += __shfl_xor(ss2, 8);
    ss2 += __shfl_xor(ss2, 16); ss2 += __shfl_xor(ss2, 32);
    if (lane == 0) atomicAdd(&PAD_F(smem, 18, 0), ss2);
  }
  __syncthreads();                                         // S1
  if (tid < 4) {
    float ch = fminf(PAD_F(smem, 18, 0)*(1.f/896.f), 10.f)*0.1f;
    float g = ch*Wpy[tid] + hurst[b]*Wpy[4 + tid] + bpy[tid];
    PAD_F(smem, 17, tid) = 1.f/(1.f + __expf(-g));
  }
  // ---- phase B: FT = [W_in;b_in;0] @ W_attn[0:64] ----
  {
    int mt = w & 1;
    bfrag a0 = ldInG(W_in, b_in, mt*16, 0);
    bfrag a1 = ldInG(W_in, b_in, mt*16, 32);
    #pragma unroll
    for (int nn = 0; nn < 2; nn++) {
      int nt = (w >> 1)*2 + nn;
      bfrag b0 = ldWG(Wat, nt*16, 0);
      bfrag b1 = ldWG(Wat, nt*16, 32);
      ffrag c = {0.f,0.f,0.f,0.f};
      c = MFMA16(a0, b0, c);
      c = MFMA16(a1, b1, c);
      stfragT(FT, mt*16, nt*16, 40, c);
    }
  }
  __syncthreads();                                         // S2
  for (int e = tid; e < 448; e += 256) {
    int s = e >> 6, n = e & 63;
    FT[n*40 + 18 + s] = f2us(Wat[(64 + s)*64 + n]);
  }
  __syncthreads();                                         // S3
  // ---- phase C: Ain = xz @ FT^T + bat -> sAin ----
  #pragma unroll
  for (int mt = 0; mt < 2; mt++) {
    int r0 = w*32 + mt*16;
    bfrag a = ldfrag(xz, r0, 40, 0);
    #pragma unroll
    for (int nt = 0; nt < 4; nt++) {
      bfrag bf = ldfrag(FT, nt*16, 40, 0);
      ffrag c = {0.f,0.f,0.f,0.f};
      c = MFMA16(a, bf, c);
      c += bat[nt*16 + (lane & 15)];
      stfrag(sAin, r0, nt*16, 72, c);
    }
  }
  __syncthreads();                                         // S4

  // ---- heads ----
  ffrag ctxr[4][2];
  for (int h = 0; h < 4; h++) {
    bfrag bq0 = ldWG(Wq, 16*h, 0), bq1 = ldWG(Wq, 16*h, 32);
    bfrag bk0 = ldWG(Wk, 16*h, 0), bk1 = ldWG(Wk, 16*h, 32);
    bfrag bv0 = ldWG(Wv, 16*h, 0), bv1 = ldWG(Wv, 16*h, 32);
    #pragma unroll
    for (int mt = 0; mt < 2; mt++) {
      int r0 = w*32 + mt*16;
      bfrag a0 = ldfrag(sAin, r0, 72, 0);
      bfrag a1 = ldfrag(sAin, r0, 72, 32);
      {
        ffrag c = {0.f,0.f,0.f,0.f};
        c = MFMA16(a0, bq0, c); c = MFMA16(a1, bq1, c);
        c += bq[16*h + (lane & 15)];
        stfrag(sQ, r0, 0, 24, c);
      }
      {
        ffrag c = {0.f,0.f,0.f,0.f};
        c = MFMA16(a0, bk0, c); c = MFMA16(a1, bk1, c);
        c += bk[16*h + (lane & 15)];
        stfrag(sK, r0, 0, 24, c);
      }
      {
        ffrag c = {0.f,0.f,0.f,0.f};
        c = MFMA16(a0, bv0, c); c = MFMA16(a1, bv1, c);
        c += bv[16*h + (lane & 15)];
        stfragT(sVT, r0, 0, 136, c);
      }
    }
    __syncthreads();                                       // Sh1
    float scale = 0.25f*PAD_F(smem, 17, h);
    bfrag qa0 = ldQK(sQ, zslot, w*32);
    bfrag qa1 = ldQK(sQ, zslot, w*32 + 16);
    ffrag sc[2][8];
    #pragma unroll
    for (int nt = 0; nt < 8; nt++) {
      bfrag kb = ldQK(sK, zslot, nt*16);
      ffrag z0 = {0.f,0.f,0.f,0.f};
      ffrag z1 = {0.f,0.f,0.f,0.f};
      sc[0][nt] = MFMA16(qa0, kb, z0);
      sc[1][nt] = MFMA16(qa1, kb, z1);
    }
    __syncthreads();                                       // Sh2
    u16* sPw = sP + w*2176;
    #pragma unroll
    for (int mt = 0; mt < 2; mt++) {
      #pragma unroll
      for (int nt = 0; nt < 8; nt++) sc[mt][nt] *= scale;
      float mx[4], sum[4];
      #pragma unroll
      for (int r = 0; r < 4; r++) {
        float m_ = sc[mt][0][r];
        #pragma unroll
        for (int nt = 1; nt < 8; nt++) m_ = fmaxf(m_, sc[mt][nt][r]);
        m_ = DPPMAX(m_, 0xB1);
        m_ = DPPMAX(m_, 0x4E);
        m_ = DPPMAX(m_, 0x141);
        m_ = DPPMAX(m_, 0x128);
        mx[r] = m_; sum[r] = 0.f;
      }
      #pragma unroll
      for (int nt = 0; nt < 8; nt++) {
        #pragma unroll
        for (int r = 0; r < 4; r++) {
          float p = __expf(sc[mt][nt][r] - mx[r]);
          sc[mt][nt][r] = p; sum[r] += p;
        }
      }
      #pragma unroll
      for (int r = 0; r < 4; r++) {
        float s_ = sum[r];
        s_ = DPPADD(s_, 0xB1);
        s_ = DPPADD(s_, 0x4E);
        s_ = DPPADD(s_, 0x141);
        s_ = DPPADD(s_, 0x128);
        sum[r] = 1.f/s_;
      }
      int rb = (lane >> 4) << 2;
      int cb = lane & 15;
      #pragma unroll
      for (int nt = 0; nt < 8; nt++) {
        #pragma unroll
        for (int r = 0; r < 4; r++)
          sPw[(rb + r)*136 + nt*16 + cb] = f2us(sc[mt][nt][r]*sum[r]);
      }
      ffrag cc = {0.f,0.f,0.f,0.f};
      #pragma unroll
      for (int ks = 0; ks < 4; ks++) {
        bfrag pa = ldfrag(sPw, 0, 136, ks*32);
        bfrag vb = ldfrag(sVT, 0, 136, ks*32);
        cc = MFMA16(pa, vb, cc);
      }
      ctxr[h][mt] = cc;
    }
    __syncthreads();                                       // Sh3
  }
  // ---- ctx -> ctxb; Wo -> sOut + pooled; pheno ----
  #pragma unroll
  for (int h = 0; h < 4; h++)
    #pragma unroll
    for (int mt = 0; mt < 2; mt++)
      stfrag(ctxb, w*32 + mt*16, 16*h, 72, ctxr[h][mt]);
  float pacc[4];
  {
    bfrag a00 = ldfrag(ctxb, w*32, 72, 0);
    bfrag a01 = ldfrag(ctxb, w*32, 72, 32);
    bfrag a10 = ldfrag(ctxb, w*32 + 16, 72, 0);
    bfrag a11 = ldfrag(ctxb, w*32 + 16, 72, 32);
    #pragma unroll
    for (int nt = 0; nt < 4; nt++) {
      bfrag b0 = ldWG(Wo, nt*16, 0);
      bfrag b1 = ldWG(Wo, nt*16, 32);
      ffrag c0 = {0.f,0.f,0.f,0.f};
      ffrag c1 = {0.f,0.f,0.f,0.f};
      c0 = MFMA16(a00, b0, c0); c0 = MFMA16(a01, b1, c0);
      c1 = MFMA16(a10, b0, c1); c1 = MFMA16(a11, b1, c1);
      float bn = bo[nt*16 + (lane & 15)];
      c0 += bn; c1 += bn;
      pacc[nt] = c0[0]+c0[1]+c0[2]+c0[3]+c1[0]+c1[1]+c1[2]+c1[3];
      stfrag(sOut, w*32, nt*16, 72, c0);
      stfrag(sOut, w*32 + 16, nt*16, 72, c1);
    }
  }
  #pragma unroll
  for (int nt = 0; nt < 4; nt++) {
    pacc[nt] += __shfl_xor(pacc[nt], 16);
    pacc[nt] += __shfl_xor(pacc[nt], 32);
    if ((lane >> 4) == 0) {
      int j = nt*16 + (lane & 15);
      atomicAdd(&PAD_F(smem, 1 + (j >> 2), j & 3), pacc[nt]);
    }
  }
  __syncthreads();                                         // S5
  {
    int col = lane & 15;
    float bn = (col < 7) ? bpn[col] : 0.f;
    bfrag b0 = ldPnG(Wpn, 0);
    bfrag b1 = ldPnG(Wpn, 32);
    #pragma unroll
    for (int mt = 0; mt < 2; mt++) {
      bfrag a0 = ldfrag(sOut, w*32 + mt*16, 72, 0);
      bfrag a1 = ldfrag(sOut, w*32 + mt*16, 72, 32);
      ffrag c = {0.f,0.f,0.f,0.f};
      c = MFMA16(a0, b0, c);
      c = MFMA16(a1, b1, c);
      c += bn;
      if (col < 7) {
        int m0 = w*32 + mt*16 + ((lane >> 4) << 2);
        #pragma unroll
        for (int r = 0; r < 4; r++)
          out[O_PHENO + (b*128 + m0 + r)*7 + col] = oclamp(c[r]);
      }
    }
  }
  if (w == 0) {
    float p = PAD_F(smem, 1 + (lane >> 2), lane & 3)*(1.f/128.f);
    float mu = p;
    mu += __shfl_xor(mu, 1); mu += __shfl_xor(mu, 2); mu += __shfl_xor(mu, 4);
    mu += __shfl_xor(mu, 8); mu += __shfl_xor(mu, 16); mu += __shfl_xor(mu, 32);
    mu *= (1.f/64.f);
    float e_ = p - mu;
    float vv = e_*e_;
    vv += __shfl_xor(vv, 1); vv += __shfl_xor(vv, 2); vv += __shfl_xor(vv, 4);
    vv += __shfl_xor(vv, 8); vv += __shfl_xor(vv, 16); vv += __shfl_xor(vv, 32);
    vv *= (1.f/64.f);
    float y = e_*rsqrtf(vv + 1e-5f)*lng[lane] + lnb[lane];
    #pragma unroll
    for (int c = 0; c < 3; c++) {
      float t_ = y*Wcrop[lane*3 + c];
      t_ += __shfl_xor(t_, 1); t_ += __shfl_xor(t_, 2); t_ += __shfl_xor(t_, 4);
      t_ += __shfl_xor(t_, 8); t_ += __shfl_xor(t_, 16); t_ += __shfl_xor(t_, 32);
      if (lane == 0) out[O_CROP + b*3 + c] = oclamp(t_ + bcrop[c]);
    }
  }
}

extern "C" void kernel_launch(void* const* d_in, const int* in_sizes, int n_in,
                              void* d_out, int out_size, void* d_ws, size_t ws_size,
                              hipStream_t stream) {
  const float* xg     = (const float*)d_in[0];
  const float* hurst  = (const float*)d_in[2];
  const float* W_in   = (const float*)d_in[3];
  const float* b_in   = (const float*)d_in[4];
  const float* W_exec = (const float*)d_in[5];
  const float* b_exec = (const float*)d_in[6];
  const float* W_meas = (const float*)d_in[7];
  const float* b_meas = (const float*)d_in[8];
  const float* Amat   = (const float*)d_in[9];
  const float* W_attn = (const float*)d_in[10];
  const float* b_attn = (const float*)d_in[11];
  const float* Wq  = (const float*)d_in[12];
  const float* bqp = (const float*)d_in[13];
  const float* Wk  = (const float*)d_in[14];
  const float* bkp = (const float*)d_in[15];
  const float* Wv  = (const float*)d_in[16];
  const float* bvp = (const float*)d_in[17];
  const float* Wo  = (const float*)d_in[18];
  const float* bop = (const float*)d_in[19];
  const float* Wpy = (const float*)d_in[20];
  const float* bpy = (const float*)d_in[21];
  const float* lng = (const float*)d_in[22];
  const float* lnb = (const float*)d_in[23];
  const float* Wcrop = (const float*)d_in[24];
  const float* bcrop = (const float*)d_in[25];
  const float* Wpn = (const float*)d_in[26];
  const float* bpn = (const float*)d_in[27];
  float* out = (float*)d_out;
  const int SMEM = 40960;   // 4 blocks/CU (163840/40960 = 4.0)
  hipFuncSetAttribute((const void*)k_attn, hipFuncAttributeMaxDynamicSharedMemorySize, SMEM);
  k_scan<<<1024, 64, 0, stream>>>(xg, W_in, b_in, W_exec, b_exec, W_meas, b_meas, Amat, out);
  k_attn<<<1024, 256, SMEM, stream>>>(xg, Wq, bqp, Wk, bkp, Wv, bvp, Wo, bop,
                                      W_in, b_in, W_attn, b_attn, Wpy, bpy, hurst,
                                      lng, lnb, Wcrop, bcrop, Wpn, bpn, out);
}

// Round 10
// 277.054 us; speedup vs baseline: 4.1435x; 1.0162x over previous
//
#include <hip/hip_runtime.h>
#include <hip/hip_bf16.h>

// DynamisCropClassifier: Kalman-scan + gated attention classifier.
// ROUND 16 == ROUND 15 with the lgkmcnt encoding fixed.
//   R9 failed to COMPILE: lgkmcnt field is 4 bits (max 15); lgkmcnt(16) is
//   not encodable. Fix: wait lgkmcnt(15) = oldest 3 of the 18 DS reads
//   retired (v0, v1, hq[0]) -- correctness identical (v0/v1 ready), ~5cy
//   stronger wait than intended, encodable.
//   Structure (from R15): asm1 issues all 18 ds_read_b128 + waits
//   lgkmcnt(15); Kalman chain (part/DPP/inn/readlane/aown/xs) runs while
//   the 15 remaining hq reads drain; asm2 = s_waitcnt lgkmcnt(0) with
//   "+v"-tied hq operands (+ sched_barrier(0), rule 18) gates only the
//   GEMV. Same instructions, same FMA chains, same values -> bit-exact
//   (absmax tripwire 0.0234375).
//   Judge by k_scan dispatch dur (R8=95 -> pred 82-90); total has +-20us
//   harness noise (R4/R6/R8 non-kernel part = 178/167/186us, same code).
//   k_attn: verbatim R12/R8 (4 blocks/CU, 40960B LDS diet, passing).

typedef unsigned short u16;
typedef __attribute__((ext_vector_type(8))) short bfrag;   // 8 x bf16 (4 VGPR)
typedef __attribute__((ext_vector_type(4))) float ffrag;   // 4 x f32 acc
typedef __attribute__((ext_vector_type(4))) float f32x4;   // 4 x f32 (4 VGPR)

#define MFMA16(a,b,c) __builtin_amdgcn_mfma_f32_16x16x32_bf16((a),(b),(c),0,0,0)
#define WSYNC() __builtin_amdgcn_wave_barrier()

// ---- output element offsets (fp32 elements) ----
#define O_CROP  0
#define O_PHENO 3072
#define O_INNOV 920576
#define O_UNC   1838080
#define O_XFIN  1839104
#define O_STATE 1846272

static __device__ __forceinline__ float i2f(int i){union{int i;float f;}u;u.i=i;return u.f;}
static __device__ __forceinline__ int f2i(float f){union{int i;float f;}u;u.f=f;return u.i;}
// DPP cross-lane add/max (VALU-speed, no LDS pipe).
#define DPPADD(v,ctrl) ((v) + i2f(__builtin_amdgcn_update_dpp(0, f2i(v), (ctrl), 0xF, 0xF, true)))
#define DPPMAX(v,ctrl) fmaxf((v), i2f(__builtin_amdgcn_update_dpp(0, f2i(v), (ctrl), 0xF, 0xF, true)))

static __device__ __forceinline__ u16 f2us(float f) {   // RNE fp32 -> bf16 bits
  union { float f; unsigned int i; } v; v.f = f;
  unsigned int r = v.i + 0x7FFFu + ((v.i >> 16) & 1u);
  return (u16)(r >> 16);
}
static __device__ __forceinline__ float oclamp(float v) {  // NaN-scrub diagnostic
  v = fmaxf(v, -1.0e30f); v = fminf(v, 1.0e30f); return v;
}
static __device__ __forceinline__ float rfl(float x) {     // wave-uniform -> SGPR
  return i2f(__builtin_amdgcn_readfirstlane(f2i(x)));
}
static __device__ __forceinline__ float rlane(float x, int l) {
  return i2f(__builtin_amdgcn_readlane(f2i(x), l));
}

// ============================ kernel 1: scan ============================
// One wave per batch element; wave-synchronous LDS (no s_barrier).
__global__ __launch_bounds__(64, 1) void k_scan(
    const float* __restrict__ xg,
    const float* __restrict__ W_in, const float* __restrict__ b_in,
    const float* __restrict__ W_exec, const float* __restrict__ b_exec,
    const float* __restrict__ W_meas, const float* __restrict__ b_meas,
    const float* __restrict__ A, float* __restrict__ out)
{
  __shared__ __align__(16) float sX[128*20];   // x[b], pitch 20
  __shared__ __align__(16) float sKt[12*52];   // K_t (t<12; frozen = row 11 after)
  __shared__ __align__(16) float sH[64];
  __shared__ __align__(16) float sInn[128*8];
  __shared__ __align__(16) float sSt[128*8];
  __shared__ __align__(16) float sM[52];
  __shared__ __align__(16) float sS[52];
  __shared__ __align__(16) float sU[52];
  const int lane = threadIdx.x;
  const int b = blockIdx.x;
  for (int e = lane; e < 128*17; e += 64) {
    int t = e / 17; int i2 = e - t*17;
    sX[t*20 + i2] = xg[b*2176 + e];
  }
  if (lane < 52) sM[lane] = (lane < 49 && (lane % 8) == 0) ? 1.f : 0.f;
  sH[lane] = 0.f;
  WSYNC();

  // A into SGPRs (wave-uniform) -- identical to round-6 passing kernel
  float As[49];
  #pragma unroll
  for (int j = 0; j < 49; j++) As[j] = rfl(A[j]);

  // fold: Wcb = W_in @ W_exec[0:64] (column `lane`)  [verbatim]
  float Wcb[17];
  float bcomb;
  {
    float acc[17];
    #pragma unroll
    for (int i2 = 0; i2 < 17; i2++) acc[i2] = 0.f;
    float bc = 0.f;
    #pragma unroll 4
    for (int p = 0; p < 64; p++) {
      float wt = W_exec[p*64 + lane];
      bc += b_in[p]*wt;
      #pragma unroll
      for (int i2 = 0; i2 < 17; i2++) acc[i2] += W_in[i2*64 + p]*wt;
    }
    #pragma unroll
    for (int i2 = 0; i2 < 17; i2++) Wcb[i2] = acc[i2];
    bcomb = bc + b_exec[lane];
  }
  float Wbot[64];
  #pragma unroll
  for (int i2 = 0; i2 < 64; i2++) Wbot[i2] = W_exec[(71 + i2)*64 + lane];
  float Wt7[7];                                // (A^T Wmid)  [verbatim]
  {
    float Wmid[7];
    #pragma unroll
    for (int s = 0; s < 7; s++) Wmid[s] = W_exec[(64 + s)*64 + lane];
    #pragma unroll
    for (int j = 0; j < 7; j++) {
      float a = 0.f;
      #pragma unroll
      for (int s = 0; s < 7; s++) a += Wmid[s]*As[s*7 + j];
      Wt7[j] = a;
    }
  }
  const int si = lane >> 3, u = lane & 7;
  const int ssx = (si < 7) ? si : 0;
  float Wm8[8];
  #pragma unroll
  for (int i2 = 0; i2 < 8; i2++) {
    float wv = W_meas[(u*8 + i2)*7 + ssx];
    Wm8[i2] = (si < 7) ? wv : 0.f;
  }
  const float bm = (si < 7 && u == 0) ? b_meas[ssx] : 0.f;
  // own A-row: same expression as round-6's xp[si]
  float Arow[7];
  #pragma unroll
  for (int j = 0; j < 7; j++) Arow[j] = As[ssx*7 + j];

  // ---- Riccati (12 iters; verbatim)
  {
    const int i = si, l2 = lane & 7;
    const bool valid = (i < 7) && (l2 < 7);
    const int ii = (i < 7) ? i : 0, ll = (l2 < 7) ? l2 : 0;
    float Ai[7], Al[7];
    #pragma unroll
    for (int j = 0; j < 7; j++) { Ai[j] = As[ii*7 + j]; Al[j] = As[ll*7 + j]; }
    for (int t = 0; t < 12; t++) {
      float Mf[49];
      #pragma unroll
      for (int q = 0; q < 12; q++) { float4 mv = ((const float4*)sM)[q];
        Mf[4*q] = mv.x; Mf[4*q+1] = mv.y; Mf[4*q+2] = mv.z; Mf[4*q+3] = mv.w; }
      Mf[48] = sM[48];
      const float pd = (t == 0) ? 0.1f : 0.5f;
      const float pm = (t == 0) ? 0.f  : -0.25f;
      float pp = 0.f;
      #pragma unroll
      for (int k = 0; k < 7; k++) {
        float md = 0.f;
        #pragma unroll
        for (int j = 0; j < 7; j++) md += Ai[j]*Mf[j*7 + k];
        pp += (pd*Ai[k] + pm*md)*Al[k];
      }
      float S_own = pp + ((i == l2) ? 1.f : 0.f);
      WSYNC();
      if (valid) sS[i*7 + l2] = S_own;
      WSYNC();
      float Srow[7], Mrow[7], Mcol[7], Mown;
      #pragma unroll
      for (int k = 0; k < 7; k++) { Srow[k] = sS[ii*7 + k]; Mrow[k] = sM[ii*7 + k]; Mcol[k] = sM[k*7 + ll]; }
      Mown = sM[ii*7 + ll];
      for (int it = 0; it < 3; it++) {           // Newton: M' = 2M - M S M
        float Uo = 0.f;
        #pragma unroll
        for (int k = 0; k < 7; k++) Uo += Srow[k]*Mcol[k];
        WSYNC();
        if (valid) sU[i*7 + l2] = Uo;
        WSYNC();
        float d = 0.f;
        #pragma unroll
        for (int k = 0; k < 7; k++) d += Mrow[k]*sU[k*7 + ll];
        float Mn = 2.f*Mown - d;
        WSYNC();
        if (valid) sM[i*7 + l2] = Mn;
        WSYNC();
        if (it < 2) {
          #pragma unroll
          for (int k = 0; k < 7; k++) { Mrow[k] = sM[ii*7 + k]; Mcol[k] = sM[k*7 + ll]; }
          Mown = Mn;
        }
      }
      if (lane < 49)
        sKt[t*52 + lane] = (((lane % 8) == 0) ? 1.f : 0.f) - 0.5f*sM[lane];
      else if (lane < 52)
        sKt[t*52 + lane] = 0.f;
    }
  }
  WSYNC();
  if (lane == 0) {                               // trace(P_fin) = trace(0.5 K)
    float tr = 0.f;
    #pragma unroll
    for (int s = 0; s < 7; s++) tr += 0.5f*(1.f - 0.5f*sM[s*8]);
    out[O_UNC + b] = oclamp(tr);
  }
  // frozen K own-row (values == round-6's Kreg[si*7+j] after t=11)
  float Kf7[7];
  #pragma unroll
  for (int j = 0; j < 7; j++) Kf7[j] = sKt[11*52 + ssx*7 + j];

  // ---- 128-step scan (bit-exact round-6 arithmetic; split-wait pipeline) ----
  float xs[7];
  #pragma unroll
  for (int s = 0; s < 7; s++) xs[s] = 0.f;
  float g0 = 0.f, g1 = 0.f, g2 = 0.f, g3 = 0.f;
  float preX = bcomb;
  #pragma unroll
  for (int i2 = 0; i2 < 17; i2++) preX += sX[i2]*Wcb[i2];

  // LDS byte offset of sH (flat ptr truncation; LDS aperture 4GiB-aligned)
  const unsigned hbase = (unsigned)(unsigned long long)(const void*)sH;
  const unsigned hpart = hbase + ((unsigned)u << 5);   // sH + u*8 floats

  // one step body; Krw[] must already hold this step's K own-row.
  #define SCAN_STEP(T)                                                        \
  {                                                                           \
    float xpo = 0.f;                                                          \
    _Pragma("unroll")                                                         \
    for (int j = 0; j < 7; j++) xpo += Arow[j]*xs[j];                         \
    float preXn = bcomb;                                                      \
    if ((T) < 127) {                                                          \
      const float4* xp4 = (const float4*)(sX + ((T)+1)*20);                   \
      float4 xa = xp4[0], xb = xp4[1], xc = xp4[2], xd = xp4[3];              \
      float xe = sX[((T)+1)*20 + 16];                                         \
      preXn += xa.x*Wcb[0];  preXn += xa.y*Wcb[1];                            \
      preXn += xa.z*Wcb[2];  preXn += xa.w*Wcb[3];                            \
      preXn += xb.x*Wcb[4];  preXn += xb.y*Wcb[5];                            \
      preXn += xb.z*Wcb[6];  preXn += xb.w*Wcb[7];                            \
      preXn += xc.x*Wcb[8];  preXn += xc.y*Wcb[9];                            \
      preXn += xc.z*Wcb[10]; preXn += xc.w*Wcb[11];                           \
      preXn += xd.x*Wcb[12]; preXn += xd.y*Wcb[13];                           \
      preXn += xd.z*Wcb[14]; preXn += xd.w*Wcb[15];                           \
      preXn += xe*Wcb[16];                                                    \
    }                                                                         \
    float pre = preX;                                                         \
    _Pragma("unroll")                                                         \
    for (int j = 0; j < 7; j++) pre += Wt7[j]*xs[j];                          \
    pre += (g0 + g1) + (g2 + g3);                                             \
    float ex = __expf(2.f*pre);                                               \
    float hn = 1.f - 2.f/(ex + 1.f);             /* tanh, Inf-safe */         \
    sH[lane] = hn;                               /* same-wave DS in-order */  \
    /* asm1: issue ALL 18 reads; wait oldest 3 (v0,v1,hq0) = lgkmcnt(15, */  \
    /* field max). DS retires in-order -> v0,v1 ready for the chain.     */  \
    f32x4 v0, v1, hq[16];                                                     \
    asm volatile(                                                             \
      "ds_read_b128 %0, %18\n\t"                                              \
      "ds_read_b128 %1, %18 offset:16\n\t"                                    \
      "ds_read_b128 %2, %19\n\t"                                              \
      "ds_read_b128 %3, %19 offset:16\n\t"                                    \
      "ds_read_b128 %4, %19 offset:32\n\t"                                    \
      "ds_read_b128 %5, %19 offset:48\n\t"                                    \
      "ds_read_b128 %6, %19 offset:64\n\t"                                    \
      "ds_read_b128 %7, %19 offset:80\n\t"                                    \
      "ds_read_b128 %8, %19 offset:96\n\t"                                    \
      "ds_read_b128 %9, %19 offset:112\n\t"                                   \
      "ds_read_b128 %10, %19 offset:128\n\t"                                  \
      "ds_read_b128 %11, %19 offset:144\n\t"                                  \
      "ds_read_b128 %12, %19 offset:160\n\t"                                  \
      "ds_read_b128 %13, %19 offset:176\n\t"                                  \
      "ds_read_b128 %14, %19 offset:192\n\t"                                  \
      "ds_read_b128 %15, %19 offset:208\n\t"                                  \
      "ds_read_b128 %16, %19 offset:224\n\t"                                  \
      "ds_read_b128 %17, %19 offset:240\n\t"                                  \
      "s_waitcnt lgkmcnt(15)"                                                 \
      : "=&v"(v0), "=&v"(v1),                                                 \
        "=&v"(hq[0]),  "=&v"(hq[1]),  "=&v"(hq[2]),  "=&v"(hq[3]),            \
        "=&v"(hq[4]),  "=&v"(hq[5]),  "=&v"(hq[6]),  "=&v"(hq[7]),            \
        "=&v"(hq[8]),  "=&v"(hq[9]),  "=&v"(hq[10]), "=&v"(hq[11]),           \
        "=&v"(hq[12]), "=&v"(hq[13]), "=&v"(hq[14]), "=&v"(hq[15])            \
      : "v"(hpart), "v"(hbase)                                                \
      : "memory");                                                            \
    __builtin_amdgcn_sched_barrier(0);                                        \
    /* ---- Kalman chain runs WHILE the 15 remaining hq reads drain ---- */   \
    float part = v0[0]*Wm8[0] + v0[1]*Wm8[1] + v0[2]*Wm8[2] + v0[3]*Wm8[3]    \
               + v1[0]*Wm8[4] + v1[1]*Wm8[5] + v1[2]*Wm8[6] + v1[3]*Wm8[7]    \
               + bm;                                                          \
    part = DPPADD(part, 0xB1);                                                \
    part = DPPADD(part, 0x4E);                                                \
    part = DPPADD(part, 0x141);                                               \
    float inn = part - xpo;                                                   \
    if (u == 0 && si < 7) sInn[(T)*8 + si] = inn;                             \
    float ir[7];                                 /* innov -> SGPRs */         \
    _Pragma("unroll")                                                         \
    for (int j = 0; j < 7; j++) ir[j] = rlane(inn, j*8);                      \
    float aown = xpo;                                                         \
    _Pragma("unroll")                                                         \
    for (int j = 0; j < 7; j++) aown += Krw[j]*ir[j];                         \
    _Pragma("unroll")                                                         \
    for (int s = 0; s < 7; s++) xs[s] = rlane(aown, s*8);                     \
    if (u == 0 && si < 7) sSt[(T)*8 + si] = aown;                             \
    /* asm2: drain remaining reads; hq tied -> GEMV data-deps on this */      \
    asm volatile(                                                             \
      "s_waitcnt lgkmcnt(0)"                                                  \
      : "+v"(hq[0]),  "+v"(hq[1]),  "+v"(hq[2]),  "+v"(hq[3]),                \
        "+v"(hq[4]),  "+v"(hq[5]),  "+v"(hq[6]),  "+v"(hq[7]),                \
        "+v"(hq[8]),  "+v"(hq[9]),  "+v"(hq[10]), "+v"(hq[11]),               \
        "+v"(hq[12]), "+v"(hq[13]), "+v"(hq[14]), "+v"(hq[15])                \
      :: "memory");                                                           \
    __builtin_amdgcn_sched_barrier(0);                                        \
    /* GEMV(h_t) for step t+1; per-accumulator order == round-6 */            \
    g0 = 0.f; g1 = 0.f; g2 = 0.f; g3 = 0.f;                                   \
    _Pragma("unroll")                                                         \
    for (int q = 0; q < 16; q++) {                                            \
      g0 += hq[q][0]*Wbot[4*q+0]; g1 += hq[q][1]*Wbot[4*q+1];                 \
      g2 += hq[q][2]*Wbot[4*q+2]; g3 += hq[q][3]*Wbot[4*q+3];                 \
    }                                                                         \
    preX = preXn;                                                             \
  }

  for (int t = 0; t < 12; t++) {                 // varying-K steps
    float Krw[7];
    #pragma unroll
    for (int j = 0; j < 7; j++) Krw[j] = sKt[t*52 + ssx*7 + j];
    SCAN_STEP(t)
  }
  {
    float Krw[7];
    #pragma unroll
    for (int j = 0; j < 7; j++) Krw[j] = Kf7[j];
    for (int t = 12; t < 128; t++) {             // frozen-K steps (hot)
      SCAN_STEP(t)
    }
  }
  #undef SCAN_STEP

  WSYNC();
  for (int e = lane; e < 896; e += 64) {         // bulk coalesced stores
    int t = e/7, s = e - t*7;
    out[O_INNOV + b*896 + e] = oclamp(sInn[t*8 + s]);
    out[O_STATE + b*896 + e] = oclamp(sSt[t*8 + s]);
  }
  if (lane < 7) out[O_XFIN + b*7 + lane] = oclamp(sSt[127*8 + lane]);
}

// ============================ kernel 2: attention ============================
static __device__ __forceinline__ bfrag ldfrag(const u16* t, int row0, int pitch, int koff) {
  int l = threadIdx.x & 63;
  return *(const bfrag*)(t + (row0 + (l & 15))*pitch + koff + ((l >> 4) << 3));
}
// Q/K fragment: groups 0-1 read data cols 0-15 (pitch 24); groups 2-3 read a
// shared 16B zero slot (same zero operand values as the old zeroed cols 16-31).
static __device__ __forceinline__ bfrag ldQK(const u16* base, const u16* zslot, int row0) {
  int l = threadIdx.x & 63;
  int g = l >> 4;
  const u16* p = (g < 2) ? (base + (row0 + (l & 15))*24 + g*8) : zslot;
  return *(const bfrag*)p;
}
static __device__ __forceinline__ void stfrag(u16* t, int row0, int col0, int pitch, ffrag d) {
  int l = threadIdx.x & 63;
  int col = col0 + (l & 15);
  int r0 = row0 + ((l >> 4) << 2);
  #pragma unroll
  for (int r = 0; r < 4; r++) t[(r0 + r)*pitch + col] = f2us(d[r]);
}
static __device__ __forceinline__ void stfragT(u16* t, int row0, int col0, int pitch, ffrag d) {
  int l = threadIdx.x & 63;
  int n = col0 + (l & 15);
  int m0 = row0 + ((l >> 4) << 2);
  ushort4 pk;
  pk.x = f2us(d[0]); pk.y = f2us(d[1]); pk.z = f2us(d[2]); pk.w = f2us(d[3]);
  *(ushort4*)(t + n*pitch + m0) = pk;
}
// --- on-the-fly global weight fragments (values == old f2us staging) ---
static __device__ __forceinline__ bfrag ldWG(const float* __restrict__ W, int n0, int koff) {
  int l = threadIdx.x & 63;
  int n = n0 + (l & 15);
  int k0 = koff + ((l >> 4) << 3);
  bfrag r;
  #pragma unroll
  for (int kk = 0; kk < 8; kk++) r[kk] = (short)f2us(W[(k0 + kk)*64 + n]);
  return r;
}
static __device__ __forceinline__ bfrag ldPnG(const float* __restrict__ Wpn, int koff) {
  int l = threadIdx.x & 63;
  int n = l & 15;
  int k0 = koff + ((l >> 4) << 3);
  bfrag r;
  #pragma unroll
  for (int kk = 0; kk < 8; kk++) {
    float v = (n < 7) ? Wpn[(k0 + kk)*7 + n] : 0.f;
    r[kk] = (short)f2us(v);
  }
  return r;
}
static __device__ __forceinline__ bfrag ldInG(const float* __restrict__ W_in,
                                              const float* __restrict__ b_in,
                                              int r0, int koff) {
  int l = threadIdx.x & 63;
  int r = r0 + (l & 15);
  int k0 = koff + ((l >> 4) << 3);
  bfrag o;
  #pragma unroll
  for (int kk = 0; kk < 8; kk++) {
    float v = 0.f;
    if (r < 17) v = W_in[r*64 + k0 + kk];
    else if (r == 17) v = b_in[k0 + kk];
    o[kk] = (short)f2us(v);
  }
  return o;
}

// scalar slot j in sAin row r's pad (bytes r*144+128 .. +144): never touched
// by any stfrag/ldfrag (cols 64-71).
#define PAD_F(smem, r, j) (((float*)((smem) + (r)*144 + 128))[j])

__global__ __launch_bounds__(256, 4) void k_attn(
    const float* __restrict__ xg,
    const float* __restrict__ Wq, const float* __restrict__ bq,
    const float* __restrict__ Wk, const float* __restrict__ bk,
    const float* __restrict__ Wv, const float* __restrict__ bv,
    const float* __restrict__ Wo, const float* __restrict__ bo,
    const float* __restrict__ W_in, const float* __restrict__ b_in,
    const float* __restrict__ Wat, const float* __restrict__ bat,
    const float* __restrict__ Wpy, const float* __restrict__ bpy,
    const float* __restrict__ hurst,
    const float* __restrict__ lng, const float* __restrict__ lnb,
    const float* __restrict__ Wcrop, const float* __restrict__ bcrop,
    const float* __restrict__ Wpn, const float* __restrict__ bpn,
    float* __restrict__ out)
{
  extern __shared__ __align__(16) char smem[];
  u16* sAin = (u16*)smem;                 // [0,18432) ; ctxb post-heads
  u16* ctxb = (u16*)smem;
  u16* xz   = (u16*)(smem + 18432);       // [18432,28672) phases A-C
  u16* sVT  = (u16*)(smem + 18432);       // heads: [18432,22784)
  u16* sOut = (u16*)(smem + 18432);       // post-heads: [18432,36864)
  u16* sP   = (u16*)(smem + 22784);       // heads post-Sh2: +w*2176 u16
  u16* FT   = (u16*)(smem + 28672);       // [28672,33792) phases B-C
  u16* sQ   = (u16*)(smem + 28672);       // heads: [28672,34816) pitch 24
  u16* sK   = (u16*)(smem + 34816);       // heads: [34816,40960) pitch 24
  const u16* zslot = (const u16*)(smem + 128);  // sAin row0 pad: 16B zeros
  const int tid = threadIdx.x;
  const int lane = tid & 63;
  const int w = tid >> 6;
  const int b = blockIdx.x;
  const float* stateg = out + O_STATE + b*896;

  // ---- phase A: staging + pad inits ----
  for (int e = tid; e < 5120; e += 256) {
    int t = e / 40, c = e - t*40;
    float v = 0.f;
    if (c < 17) v = xg[b*2176 + t*17 + c];
    else if (c == 17) v = 1.0f;
    else if (c < 25) v = stateg[t*7 + (c - 18)];
    xz[e] = f2us(v);
  }
  if (tid < 64) PAD_F(smem, 1 + (tid >> 2), tid & 3) = 0.f;   // pooled acc
  else if (tid == 80) PAD_F(smem, 18, 0) = 0.f;               // energy
  else if (tid == 81) { int4 z = {0,0,0,0}; *(int4*)(smem + 128) = z; } // zero slot
  __syncthreads();                                         // S0 (init visible)
  {
    float ss2 = 0.f;
    for (int e = tid; e < 896; e += 256) {
      float iv = out[O_INNOV + b*896 + e];
      ss2 += iv*iv;
    }
    ss2 += __shfl_xor(ss2, 1);  ss2 += __shfl_xor(ss2, 2);
    ss2 += __shfl_xor(ss2, 4);  ss2 += __shfl_xor(ss2, 8);
    ss2 += __shfl_xor(ss2, 16); ss2 += __shfl_xor(ss2, 32);
    if (lane == 0) atomicAdd(&PAD_F(smem, 18, 0), ss2);
  }
  __syncthreads();                                         // S1
  if (tid < 4) {
    float ch = fminf(PAD_F(smem, 18, 0)*(1.f/896.f), 10.f)*0.1f;
    float g = ch*Wpy[tid] + hurst[b]*Wpy[4 + tid] + bpy[tid];
    PAD_F(smem, 17, tid) = 1.f/(1.f + __expf(-g));
  }
  // ---- phase B: FT = [W_in;b_in;0] @ W_attn[0:64] ----
  {
    int mt = w & 1;
    bfrag a0 = ldInG(W_in, b_in, mt*16, 0);
    bfrag a1 = ldInG(W_in, b_in, mt*16, 32);
    #pragma unroll
    for (int nn = 0; nn < 2; nn++) {
      int nt = (w >> 1)*2 + nn;
      bfrag b0 = ldWG(Wat, nt*16, 0);
      bfrag b1 = ldWG(Wat, nt*16, 32);
      ffrag c = {0.f,0.f,0.f,0.f};
      c = MFMA16(a0, b0, c);
      c = MFMA16(a1, b1, c);
      stfragT(FT, mt*16, nt*16, 40, c);
    }
  }
  __syncthreads();                                         // S2
  for (int e = tid; e < 448; e += 256) {
    int s = e >> 6, n = e & 63;
    FT[n*40 + 18 + s] = f2us(Wat[(64 + s)*64 + n]);
  }
  __syncthreads();                                         // S3
  // ---- phase C: Ain = xz @ FT^T + bat -> sAin ----
  #pragma unroll
  for (int mt = 0; mt < 2; mt++) {
    int r0 = w*32 + mt*16;
    bfrag a = ldfrag(xz, r0, 40, 0);
    #pragma unroll
    for (int nt = 0; nt < 4; nt++) {
      bfrag bf = ldfrag(FT, nt*16, 40, 0);
      ffrag c = {0.f,0.f,0.f,0.f};
      c = MFMA16(a, bf, c);
      c += bat[nt*16 + (lane & 15)];
      stfrag(sAin, r0, nt*16, 72, c);
    }
  }
  __syncthreads();                                         // S4

  // ---- heads ----
  ffrag ctxr[4][2];
  for (int h = 0; h < 4; h++) {
    bfrag bq0 = ldWG(Wq, 16*h, 0), bq1 = ldWG(Wq, 16*h, 32);
    bfrag bk0 = ldWG(Wk, 16*h, 0), bk1 = ldWG(Wk, 16*h, 32);
    bfrag bv0 = ldWG(Wv, 16*h, 0), bv1 = ldWG(Wv, 16*h, 32);
    #pragma unroll
    for (int mt = 0; mt < 2; mt++) {
      int r0 = w*32 + mt*16;
      bfrag a0 = ldfrag(sAin, r0, 72, 0);
      bfrag a1 = ldfrag(sAin, r0, 72, 32);
      {
        ffrag c = {0.f,0.f,0.f,0.f};
        c = MFMA16(a0, bq0, c); c = MFMA16(a1, bq1, c);
        c += bq[16*h + (lane & 15)];
        stfrag(sQ, r0, 0, 24, c);
      }
      {
        ffrag c = {0.f,0.f,0.f,0.f};
        c = MFMA16(a0, bk0, c); c = MFMA16(a1, bk1, c);
        c += bk[16*h + (lane & 15)];
        stfrag(sK, r0, 0, 24, c);
      }
      {
        ffrag c = {0.f,0.f,0.f,0.f};
        c = MFMA16(a0, bv0, c); c = MFMA16(a1, bv1, c);
        c += bv[16*h + (lane & 15)];
        stfragT(sVT, r0, 0, 136, c);
      }
    }
    __syncthreads();                                       // Sh1
    float scale = 0.25f*PAD_F(smem, 17, h);
    bfrag qa0 = ldQK(sQ, zslot, w*32);
    bfrag qa1 = ldQK(sQ, zslot, w*32 + 16);
    ffrag sc[2][8];
    #pragma unroll
    for (int nt = 0; nt < 8; nt++) {
      bfrag kb = ldQK(sK, zslot, nt*16);
      ffrag z0 = {0.f,0.f,0.f,0.f};
      ffrag z1 = {0.f,0.f,0.f,0.f};
      sc[0][nt] = MFMA16(qa0, kb, z0);
      sc[1][nt] = MFMA16(qa1, kb, z1);
    }
    __syncthreads();                                       // Sh2
    u16* sPw = sP + w*2176;
    #pragma unroll
    for (int mt = 0; mt < 2; mt++) {
      #pragma unroll
      for (int nt = 0; nt < 8; nt++) sc[mt][nt] *= scale;
      float mx[4], sum[4];
      #pragma unroll
      for (int r = 0; r < 4; r++) {
        float m_ = sc[mt][0][r];
        #pragma unroll
        for (int nt = 1; nt < 8; nt++) m_ = fmaxf(m_, sc[mt][nt][r]);
        m_ = DPPMAX(m_, 0xB1);
        m_ = DPPMAX(m_, 0x4E);
        m_ = DPPMAX(m_, 0x141);
        m_ = DPPMAX(m_, 0x128);
        mx[r] = m_; sum[r] = 0.f;
      }
      #pragma unroll
      for (int nt = 0; nt < 8; nt++) {
        #pragma unroll
        for (int r = 0; r < 4; r++) {
          float p = __expf(sc[mt][nt][r] - mx[r]);
          sc[mt][nt][r] = p; sum[r] += p;
        }
      }
      #pragma unroll
      for (int r = 0; r < 4; r++) {
        float s_ = sum[r];
        s_ = DPPADD(s_, 0xB1);
        s_ = DPPADD(s_, 0x4E);
        s_ = DPPADD(s_, 0x141);
        s_ = DPPADD(s_, 0x128);
        sum[r] = 1.f/s_;
      }
      int rb = (lane >> 4) << 2;
      int cb = lane & 15;
      #pragma unroll
      for (int nt = 0; nt < 8; nt++) {
        #pragma unroll
        for (int r = 0; r < 4; r++)
          sPw[(rb + r)*136 + nt*16 + cb] = f2us(sc[mt][nt][r]*sum[r]);
      }
      ffrag cc = {0.f,0.f,0.f,0.f};
      #pragma unroll
      for (int ks = 0; ks < 4; ks++) {
        bfrag pa = ldfrag(sPw, 0, 136, ks*32);
        bfrag vb = ldfrag(sVT, 0, 136, ks*32);
        cc = MFMA16(pa, vb, cc);
      }
      ctxr[h][mt] = cc;
    }
    __syncthreads();                                       // Sh3
  }
  // ---- ctx -> ctxb; Wo -> sOut + pooled; pheno ----
  #pragma unroll
  for (int h = 0; h < 4; h++)
    #pragma unroll
    for (int mt = 0; mt < 2; mt++)
      stfrag(ctxb, w*32 + mt*16, 16*h, 72, ctxr[h][mt]);
  float pacc[4];
  {
    bfrag a00 = ldfrag(ctxb, w*32, 72, 0);
    bfrag a01 = ldfrag(ctxb, w*32, 72, 32);
    bfrag a10 = ldfrag(ctxb, w*32 + 16, 72, 0);
    bfrag a11 = ldfrag(ctxb, w*32 + 16, 72, 32);
    #pragma unroll
    for (int nt = 0; nt < 4; nt++) {
      bfrag b0 = ldWG(Wo, nt*16, 0);
      bfrag b1 = ldWG(Wo, nt*16, 32);
      ffrag c0 = {0.f,0.f,0.f,0.f};
      ffrag c1 = {0.f,0.f,0.f,0.f};
      c0 = MFMA16(a00, b0, c0); c0 = MFMA16(a01, b1, c0);
      c1 = MFMA16(a10, b0, c1); c1 = MFMA16(a11, b1, c1);
      float bn = bo[nt*16 + (lane & 15)];
      c0 += bn; c1 += bn;
      pacc[nt] = c0[0]+c0[1]+c0[2]+c0[3]+c1[0]+c1[1]+c1[2]+c1[3];
      stfrag(sOut, w*32, nt*16, 72, c0);
      stfrag(sOut, w*32 + 16, nt*16, 72, c1);
    }
  }
  #pragma unroll
  for (int nt = 0; nt < 4; nt++) {
    pacc[nt] += __shfl_xor(pacc[nt], 16);
    pacc[nt] += __shfl_xor(pacc[nt], 32);
    if ((lane >> 4) == 0) {
      int j = nt*16 + (lane & 15);
      atomicAdd(&PAD_F(smem, 1 + (j >> 2), j & 3), pacc[nt]);
    }
  }
  __syncthreads();                                         // S5
  {
    int col = lane & 15;
    float bn = (col < 7) ? bpn[col] : 0.f;
    bfrag b0 = ldPnG(Wpn, 0);
    bfrag b1 = ldPnG(Wpn, 32);
    #pragma unroll
    for (int mt = 0; mt < 2; mt++) {
      bfrag a0 = ldfrag(sOut, w*32 + mt*16, 72, 0);
      bfrag a1 = ldfrag(sOut, w*32 + mt*16, 72, 32);
      ffrag c = {0.f,0.f,0.f,0.f};
      c = MFMA16(a0, b0, c);
      c = MFMA16(a1, b1, c);
      c += bn;
      if (col < 7) {
        int m0 = w*32 + mt*16 + ((lane >> 4) << 2);
        #pragma unroll
        for (int r = 0; r < 4; r++)
          out[O_PHENO + (b*128 + m0 + r)*7 + col] = oclamp(c[r]);
      }
    }
  }
  if (w == 0) {
    float p = PAD_F(smem, 1 + (lane >> 2), lane & 3)*(1.f/128.f);
    float mu = p;
    mu += __shfl_xor(mu, 1); mu += __shfl_xor(mu, 2); mu += __shfl_xor(mu, 4);
    mu += __shfl_xor(mu, 8); mu += __shfl_xor(mu, 16); mu += __shfl_xor(mu, 32);
    mu *= (1.f/64.f);
    float e_ = p - mu;
    float vv = e_*e_;
    vv += __shfl_xor(vv, 1); vv += __shfl_xor(vv, 2); vv += __shfl_xor(vv, 4);
    vv += __shfl_xor(vv, 8); vv += __shfl_xor(vv, 16); vv += __shfl_xor(vv, 32);
    vv *= (1.f/64.f);
    float y = e_*rsqrtf(vv + 1e-5f)*lng[lane] + lnb[lane];
    #pragma unroll
    for (int c = 0; c < 3; c++) {
      float t_ = y*Wcrop[lane*3 + c];
      t_ += __shfl_xor(t_, 1); t_ += __shfl_xor(t_, 2); t_ += __shfl_xor(t_, 4);
      t_ += __shfl_xor(t_, 8); t_ += __shfl_xor(t_, 16); t_ += __shfl_xor(t_, 32);
      if (lane == 0) out[O_CROP + b*3 + c] = oclamp(t_ + bcrop[c]);
    }
  }
}

extern "C" void kernel_launch(void* const* d_in, const int* in_sizes, int n_in,
                              void* d_out, int out_size, void* d_ws, size_t ws_size,
                              hipStream_t stream) {
  const float* xg     = (const float*)d_in[0];
  const float* hurst  = (const float*)d_in[2];
  const float* W_in   = (const float*)d_in[3];
  const float* b_in   = (const float*)d_in[4];
  const float* W_exec = (const float*)d_in[5];
  const float* b_exec = (const float*)d_in[6];
  const float* W_meas = (const float*)d_in[7];
  const float* b_meas = (const float*)d_in[8];
  const float* Amat   = (const float*)d_in[9];
  const float* W_attn = (const float*)d_in[10];
  const float* b_attn = (const float*)d_in[11];
  const float* Wq  = (const float*)d_in[12];
  const float* bqp = (const float*)d_in[13];
  const float* Wk  = (const float*)d_in[14];
  const float* bkp = (const float*)d_in[15];
  const float* Wv  = (const float*)d_in[16];
  const float* bvp = (const float*)d_in[17];
  const float* Wo  = (const float*)d_in[18];
  const float* bop = (const float*)d_in[19];
  const float* Wpy = (const float*)d_in[20];
  const float* bpy = (const float*)d_in[21];
  const float* lng = (const float*)d_in[22];
  const float* lnb = (const float*)d_in[23];
  const float* Wcrop = (const float*)d_in[24];
  const float* bcrop = (const float*)d_in[25];
  const float* Wpn = (const float*)d_in[26];
  const float* bpn = (const float*)d_in[27];
  float* out = (float*)d_out;
  const int SMEM = 40960;   // 4 blocks/CU (163840/40960 = 4.0)
  hipFuncSetAttribute((const void*)k_attn, hipFuncAttributeMaxDynamicSharedMemorySize, SMEM);
  k_scan<<<1024, 64, 0, stream>>>(xg, W_in, b_in, W_exec, b_exec, W_meas, b_meas, Amat, out);
  k_attn<<<1024, 256, SMEM, stream>>>(xg, Wq, bqp, Wk, bkp, Wv, bvp, Wo, bop,
                                      W_in, b_in, W_attn, b_attn, Wpy, bpy, hurst,
                                      lng, lnb, Wcrop, bcrop, Wpn, bpn, out);
}